// Round 1
// baseline (2183.749 us; speedup 1.0000x reference)
//
#include <hip/hip_runtime.h>
#include <math.h>

#define BB 2
#define TT 2048
#define DD 1024
#define HH 16
#define HDD 32
#define INNERD 512
#define FFD 4096
#define NPROJ 2560     // D + 3*INNER
#define CATD 3072      // 3*D
#define MROWS (BB*TT)  // 4096
#define CHUNK 128
#define NCH (TT/CHUNK) // 16

// ---------------------------------------------------------------- layernorm
__global__ __launch_bounds__(256) void layernorm_k(
    const float* __restrict__ x, const float* __restrict__ g,
    const float* __restrict__ bta, float* __restrict__ y)
{
    int row = blockIdx.x;
    const float* xr = x + (size_t)row * DD;
    float s = 0.f, s2 = 0.f;
    for (int i = threadIdx.x; i < DD; i += 256) {
        float v = xr[i]; s += v; s2 += v * v;
    }
    #pragma unroll
    for (int off = 32; off > 0; off >>= 1) {
        s  += __shfl_xor(s,  off, 64);
        s2 += __shfl_xor(s2, off, 64);
    }
    __shared__ float rs[4], rs2[4];
    int wid = threadIdx.x >> 6;
    if ((threadIdx.x & 63) == 0) { rs[wid] = s; rs2[wid] = s2; }
    __syncthreads();
    s  = rs[0] + rs[1] + rs[2] + rs[3];
    s2 = rs2[0] + rs2[1] + rs2[2] + rs2[3];
    float mean = s * (1.0f / DD);
    float var  = s2 * (1.0f / DD) - mean * mean;
    float rstd = rsqrtf(var + 1e-5f);
    float* yr = y + (size_t)row * DD;
    for (int i = threadIdx.x; i < DD; i += 256)
        yr[i] = (xr[i] - mean) * rstd * g[i] + bta[i];
}

// ---------------------------------------------------------------- fp32 GEMM
// C[m, coff+n] = epilogue(A[m,:K] @ B[:K,n] + bias[n])
// EPI 0: plain   EPI 1: exact gelu
// EPI 2: residual + sigmoid(gate)*v, *mask   EPI 3: (e0 + v)*mask
template<int EPI>
__global__ __launch_bounds__(256) void gemm_fp32(
    const float* __restrict__ A, int lda,
    const float* __restrict__ Bm, int ldb,
    const float* __restrict__ bias,
    float* __restrict__ C, int ldc, int coff,
    int K,
    const float* __restrict__ e0, int e0ld,
    const float* __restrict__ e1,
    const float* __restrict__ mask)
{
    __shared__ float As[16][65];   // As[k][m], +1 pad breaks write conflicts
    __shared__ float Bs[16][64];   // Bs[k][n]
    const int tid = threadIdx.x;
    const int tx = tid & 15, ty = tid >> 4;
    const int m0 = blockIdx.y * 64, n0 = blockIdx.x * 64;
    const int ka = tid & 15, ma = tid >> 4;
    const int nb = tid & 63, kb = tid >> 6;
    float acc[4][4] = {};
    for (int k0 = 0; k0 < K; k0 += 16) {
        #pragma unroll
        for (int i = 0; i < 4; i++)
            As[ka][ma + 16*i] = A[(size_t)(m0 + ma + 16*i) * lda + k0 + ka];
        #pragma unroll
        for (int i = 0; i < 4; i++)
            Bs[kb + 4*i][nb] = Bm[(size_t)(k0 + kb + 4*i) * ldb + n0 + nb];
        __syncthreads();
        #pragma unroll
        for (int k = 0; k < 16; k++) {
            float a[4], b[4];
            #pragma unroll
            for (int i = 0; i < 4; i++) a[i] = As[k][ty*4 + i];
            #pragma unroll
            for (int j = 0; j < 4; j++) b[j] = Bs[k][tx*4 + j];
            #pragma unroll
            for (int i = 0; i < 4; i++)
                #pragma unroll
                for (int j = 0; j < 4; j++)
                    acc[i][j] = fmaf(a[i], b[j], acc[i][j]);
        }
        __syncthreads();
    }
    #pragma unroll
    for (int i = 0; i < 4; i++) {
        int row = m0 + ty*4 + i;
        #pragma unroll
        for (int j = 0; j < 4; j++) {
            int col = n0 + tx*4 + j;
            float v = acc[i][j] + bias[col];
            if constexpr (EPI == 1) {
                v = 0.5f * v * (1.0f + erff(v * 0.70710678118654752f));
            } else if constexpr (EPI == 2) {
                float g  = e0[(size_t)row * e0ld + col];
                float sg = 1.0f / (1.0f + expf(-g));
                v = e1[(size_t)row * DD + col] + sg * v;
                v *= mask[row];
            } else if constexpr (EPI == 3) {
                v = (e0[(size_t)row * e0ld + col] + v) * mask[row];
            }
            C[(size_t)row * ldc + coff + col] = v;
        }
    }
}

// ---------------------------------------------------------------- dwconv
template<int KW>
__global__ __launch_bounds__(256) void dwconv_k(
    const float* __restrict__ x, const float* __restrict__ w,
    const float* __restrict__ bias, float* __restrict__ out, int coff)
{
    int idx = blockIdx.x * 256 + threadIdx.x;   // < MROWS*DD
    int cL  = idx & (DD - 1);
    int row = idx >> 10;
    int t   = row & (TT - 1);
    float acc = bias[cL];
    #pragma unroll
    for (int i = 0; i < KW; i++) {
        int tt = t - (KW - 1) + i;
        if (tt >= 0)
            acc = fmaf(w[cL * KW + i], x[(size_t)(row - (KW - 1) + i) * DD + cL], acc);
    }
    out[(size_t)row * CATD + coff + cL] = acc;
}

// ---------------------------------------------------------------- attention
__device__ __forceinline__ float phi_f(float x) {
    return x > 0.f ? x + 1.f : expf(x);   // elu(x)+1
}

// Phase A: per-(b,h,chunk) local sums of k outer v and k. One wave per block.
// Lane ownership: e = lane&31, d in [ (lane>>5)*16 , +16 )
__global__ __launch_bounds__(64) void attn_sums(
    const float* __restrict__ proj, const float* __restrict__ mask,
    float* __restrict__ kvsum, float* __restrict__ kssum)
{
    int blk = blockIdx.x;              // bh*NCH + c
    int c  = blk & (NCH - 1);
    int bh = blk >> 4;
    int b  = bh >> 4, hh = bh & (HH - 1);
    int lane = threadIdx.x;
    int e = lane & 31, d0 = (lane >> 5) * 16;
    __shared__ float sk[32], sv[32];
    float kv[16], ksl[16];
    #pragma unroll
    for (int j = 0; j < 16; j++) { kv[j] = 0.f; ksl[j] = 0.f; }
    int rbase = b * TT + c * CHUNK;
    for (int t = 0; t < CHUNK; t++) {
        int row = rbase + t;
        float m = mask[row];
        if (lane < 32)
            sk[lane] = phi_f(proj[(size_t)row * NPROJ + DD + INNERD + hh * 32 + lane]) * m;
        else
            sv[lane - 32] = proj[(size_t)row * NPROJ + DD + 2 * INNERD + hh * 32 + (lane - 32)] * m;
        __syncthreads();
        float ve = sv[e];
        #pragma unroll
        for (int j = 0; j < 16; j++) {
            float kval = sk[d0 + j];
            kv[j] = fmaf(kval, ve, kv[j]);
            ksl[j] += kval;
        }
        __syncthreads();
    }
    size_t base = (size_t)blk * 1024;
    #pragma unroll
    for (int j = 0; j < 16; j++)
        kvsum[base + (size_t)(d0 + j) * 32 + e] = kv[j];
    if (e == 0) {
        #pragma unroll
        for (int j = 0; j < 16; j++)
            kssum[blk * 32 + d0 + j] = ksl[j];
    }
}

// Phase B: exclusive prefix over chunks, per (b,h). 32 blocks.
__global__ __launch_bounds__(256) void attn_prefix(
    const float* __restrict__ kvsum, const float* __restrict__ kssum,
    float* __restrict__ kvpref, float* __restrict__ kspref)
{
    int bh = blockIdx.x;
    int tid = threadIdx.x;
    float run[4] = {0.f, 0.f, 0.f, 0.f};
    for (int c = 0; c < NCH; c++) {
        size_t base = (size_t)(bh * NCH + c) * 1024 + tid * 4;
        #pragma unroll
        for (int q = 0; q < 4; q++) {
            kvpref[base + q] = run[q];
            run[q] += kvsum[base + q];
        }
    }
    if (tid < 32) {
        float r = 0.f;
        for (int c = 0; c < NCH; c++) {
            kspref[(bh * NCH + c) * 32 + tid] = r;
            r += kssum[(bh * NCH + c) * 32 + tid];
        }
    }
}

// Phase C: in-chunk sequential scan producing outputs.
__global__ __launch_bounds__(64) void attn_scan(
    const float* __restrict__ proj, const float* __restrict__ mask,
    const float* __restrict__ kvpref, const float* __restrict__ kspref,
    float* __restrict__ attn_out)
{
    int blk = blockIdx.x;
    int c  = blk & (NCH - 1);
    int bh = blk >> 4;
    int b  = bh >> 4, hh = bh & (HH - 1);
    int lane = threadIdx.x;
    int e = lane & 31, d0 = (lane >> 5) * 16;
    __shared__ float sq[32], sk[32], sv[32];
    float kv[16], ksl[16];
    size_t base = (size_t)blk * 1024;
    #pragma unroll
    for (int j = 0; j < 16; j++) kv[j] = kvpref[base + (size_t)(d0 + j) * 32 + e];
    #pragma unroll
    for (int j = 0; j < 16; j++) ksl[j] = kspref[blk * 32 + d0 + j];
    int rbase = b * TT + c * CHUNK;
    for (int t = 0; t < CHUNK; t++) {
        int row = rbase + t;
        float m = mask[row];
        if (lane < 32) {
            sq[lane] = phi_f(proj[(size_t)row * NPROJ + DD + hh * 32 + lane]) * m;
            sk[lane] = phi_f(proj[(size_t)row * NPROJ + DD + INNERD + hh * 32 + lane]) * m;
        } else {
            sv[lane - 32] = proj[(size_t)row * NPROJ + DD + 2 * INNERD + hh * 32 + (lane - 32)] * m;
        }
        __syncthreads();
        float ve = sv[e];
        float num = 0.f, den = 0.f;
        #pragma unroll
        for (int j = 0; j < 16; j++) {
            float kval = sk[d0 + j], qval = sq[d0 + j];
            kv[j]  = fmaf(kval, ve, kv[j]);   // inclusive cumsum
            ksl[j] += kval;
            num = fmaf(qval, kv[j],  num);
            den = fmaf(qval, ksl[j], den);
        }
        num += __shfl_xor(num, 32, 64);
        den += __shfl_xor(den, 32, 64);
        if (lane < 32)
            attn_out[(size_t)row * INNERD + hh * 32 + e] = num / (den + 1e-6f) * m;
        __syncthreads();
    }
}

// ---------------------------------------------------------------- launch
extern "C" void kernel_launch(void* const* d_in, const int* in_sizes, int n_in,
                              void* d_out, int out_size, void* d_ws, size_t ws_size,
                              hipStream_t stream)
{
    const float* inputs = (const float*)d_in[0];
    const float* mask   = (const float*)d_in[1];
    const float* ln1_g  = (const float*)d_in[2];
    const float* ln1_b  = (const float*)d_in[3];
    const float* W_in   = (const float*)d_in[4];
    const float* b_in   = (const float*)d_in[5];
    const float* W_c    = (const float*)d_in[6];
    const float* b_c    = (const float*)d_in[7];
    const float* w_t    = (const float*)d_in[8];
    const float* b_t    = (const float*)d_in[9];
    const float* w_p    = (const float*)d_in[10];
    const float* b_p    = (const float*)d_in[11];
    const float* W_mix  = (const float*)d_in[12];
    const float* b_mix  = (const float*)d_in[13];
    const float* ln2_g  = (const float*)d_in[14];
    const float* ln2_b  = (const float*)d_in[15];
    const float* W1     = (const float*)d_in[16];
    const float* b1     = (const float*)d_in[17];
    const float* W2     = (const float*)d_in[18];
    const float* b2     = (const float*)d_in[19];
    float* out = (float*)d_out;
    float* ws  = (float*)d_ws;

    // workspace layout (floats). ffn1 aliases [normed|proj|attn] (all dead
    // by the time W1 runs): 4096*4096 == 4096*(1024+2560+512) exactly.
    float* normed = ws;                                  // 4096*1024
    float* proj   = normed + (size_t)MROWS * DD;         // 4096*2560
    float* attn   = proj   + (size_t)MROWS * NPROJ;      // 4096*512
    float* cat    = attn   + (size_t)MROWS * INNERD;     // 4096*3072
    float* out1   = cat    + (size_t)MROWS * CATD;       // 4096*1024
    float* hbuf   = out1   + (size_t)MROWS * DD;         // 4096*1024
    float* kvsum  = hbuf   + (size_t)MROWS * DD;         // 512*1024
    float* kvpref = kvsum  + 512 * 1024;                 // 512*1024
    float* kssum  = kvpref + 512 * 1024;                 // 512*32
    float* kspref = kssum  + 512 * 32;                   // 512*32
    float* ffn1   = ws;                                  // 4096*4096 (alias)

    // 1. LN1
    layernorm_k<<<MROWS, 256, 0, stream>>>(inputs, ln1_g, ln1_b, normed);
    // 2. proj = normed @ W_in + b_in   (gate|q|k|v)
    gemm_fp32<0><<<dim3(NPROJ/64, MROWS/64), 256, 0, stream>>>(
        normed, DD, W_in, NPROJ, b_in, proj, NPROJ, 0, DD, nullptr, 0, nullptr, nullptr);
    // 3. chunked causal linear attention -> attn (M x 512)
    attn_sums  <<<32 * NCH, 64, 0, stream>>>(proj, mask, kvsum, kssum);
    attn_prefix<<<32, 256, 0, stream>>>(kvsum, kssum, kvpref, kspref);
    attn_scan  <<<32 * NCH, 64, 0, stream>>>(proj, mask, kvpref, kspref, attn);
    // 4. depthwise causal convs -> cat[:,D:2D], cat[:,2D:3D]
    dwconv_k<3> <<<MROWS * DD / 256, 256, 0, stream>>>(normed, w_t, b_t, cat, DD);
    dwconv_k<15><<<MROWS * DD / 256, 256, 0, stream>>>(normed, w_p, b_p, cat, 2 * DD);
    // 5. cat[:,0:D] = attn @ W_c + b_c
    gemm_fp32<0><<<dim3(DD/64, MROWS/64), 256, 0, stream>>>(
        attn, INNERD, W_c, DD, b_c, cat, CATD, 0, INNERD, nullptr, 0, nullptr, nullptr);
    // 6. out1 = (inputs + sigmoid(gate) * (cat @ W_mix + b_mix)) * mask
    gemm_fp32<2><<<dim3(DD/64, MROWS/64), 256, 0, stream>>>(
        cat, CATD, W_mix, DD, b_mix, out1, DD, 0, CATD, proj, NPROJ, inputs, mask);
    // 7. LN2
    layernorm_k<<<MROWS, 256, 0, stream>>>(out1, ln2_g, ln2_b, hbuf);
    // 8. ffn1 = gelu(hbuf @ W1 + b1)
    gemm_fp32<1><<<dim3(FFD/64, MROWS/64), 256, 0, stream>>>(
        hbuf, DD, W1, FFD, b1, ffn1, FFD, 0, DD, nullptr, 0, nullptr, nullptr);
    // 9. out = (out1 + ffn1 @ W2 + b2) * mask
    gemm_fp32<3><<<dim3(DD/64, MROWS/64), 256, 0, stream>>>(
        ffn1, FFD, W2, DD, b2, out, DD, 0, FFD, out1, DD, nullptr, mask);
}

// Round 2
// 716.671 us; speedup vs baseline: 3.0471x; 3.0471x over previous
//
#include <hip/hip_runtime.h>
#include <math.h>

#define BB 2
#define TT 2048
#define DD 1024
#define HH 16
#define INNERD 512
#define FFD 4096
#define NPROJ 2560     // D + 3*INNER
#define CATD 3072      // 3*D
#define MROWS (BB*TT)  // 4096
#define CHUNK 128
#define NCH (TT/CHUNK) // 16

typedef __bf16 bf16;
typedef __attribute__((ext_vector_type(8))) __bf16 bf16x8;
typedef __attribute__((ext_vector_type(4))) float f32x4;

// ---------------------------------------------------------------- layernorm -> bf16
__global__ __launch_bounds__(256) void layernorm_k(
    const float* __restrict__ x, const float* __restrict__ g,
    const float* __restrict__ bta, bf16* __restrict__ y)
{
    int row = blockIdx.x;
    const float* xr = x + (size_t)row * DD;
    float s = 0.f, s2 = 0.f;
    for (int i = threadIdx.x; i < DD; i += 256) {
        float v = xr[i]; s += v; s2 += v * v;
    }
    #pragma unroll
    for (int off = 32; off > 0; off >>= 1) {
        s  += __shfl_xor(s,  off, 64);
        s2 += __shfl_xor(s2, off, 64);
    }
    __shared__ float rs[4], rs2[4];
    int wid = threadIdx.x >> 6;
    if ((threadIdx.x & 63) == 0) { rs[wid] = s; rs2[wid] = s2; }
    __syncthreads();
    s  = rs[0] + rs[1] + rs[2] + rs[3];
    s2 = rs2[0] + rs2[1] + rs2[2] + rs2[3];
    float mean = s * (1.0f / DD);
    float var  = s2 * (1.0f / DD) - mean * mean;
    float rstd = rsqrtf(var + 1e-5f);
    bf16* yr = y + (size_t)row * DD;
    for (int i = threadIdx.x; i < DD; i += 256)
        yr[i] = (bf16)((xr[i] - mean) * rstd * g[i] + bta[i]);
}

// ---------------------------------------------------------------- weight transpose fp32(K,N) -> bf16(N,K)
__global__ __launch_bounds__(256) void transpose_cvt(
    const float* __restrict__ W, bf16* __restrict__ Wt, int Kd, int Nd)
{
    __shared__ float t[32][33];
    int nb = blockIdx.x * 32, kb = blockIdx.y * 32;
    int tx = threadIdx.x & 31, ty = threadIdx.x >> 5;   // 32 x 8
    #pragma unroll
    for (int r = 0; r < 32; r += 8)
        t[ty + r][tx] = W[(size_t)(kb + ty + r) * Nd + nb + tx];
    __syncthreads();
    #pragma unroll
    for (int r = 0; r < 32; r += 8)
        Wt[(size_t)(nb + ty + r) * Kd + kb + tx] = (bf16)t[tx][ty + r];
}

// ---------------------------------------------------------------- MFMA GEMM
// C = epilogue(A[M,K] @ Bt[N,K]^T + bias)
// EPI 0: plain -> bf16      EPI 1: exact gelu -> bf16
// EPI 2: (res + sigmoid(gate)*v)*mask -> fp32
// EPI 3: (res + v)*mask -> fp32
template<int EPI>
__global__ __launch_bounds__(256) void gemm_mfma(
    const bf16* __restrict__ A,  int lda,
    const bf16* __restrict__ Bt, int ldb,
    const float* __restrict__ bias,
    float* __restrict__ Cf, bf16* __restrict__ Cb, int ldc,
    int K,
    const bf16* __restrict__ gate, int gld,
    const float* __restrict__ res,
    const float* __restrict__ mask)
{
    __shared__ bf16 As[128 * 32];
    __shared__ bf16 Bs[128 * 32];
    const int tid  = threadIdx.x;
    const int wave = tid >> 6, lane = tid & 63;
    const int m0 = blockIdx.y * 128, n0 = blockIdx.x * 128;
    const int wr = wave >> 1, wc = wave & 1;
    const int lrow = lane >> 2;          // staging row within 16-row chunk
    const int lcol = (lane & 3) * 8;     // staging k offset (elems)
    const int fm = lane & 15;            // fragment m/n within 16-tile
    const int fk = (lane >> 4) * 8;      // fragment k offset

    f32x4 acc[4][4];
    #pragma unroll
    for (int i = 0; i < 4; i++)
        #pragma unroll
        for (int j = 0; j < 4; j++)
            acc[i][j] = (f32x4){0.f, 0.f, 0.f, 0.f};

    for (int k0 = 0; k0 < K; k0 += 32) {
        #pragma unroll
        for (int r = 0; r < 2; r++) {
            int c = r * 4 + wave;                 // 16-row chunk index 0..7
            int row = c * 16 + lrow;
            const bf16* ga = A  + (size_t)(m0 + row) * lda + k0 + lcol;
            const bf16* gb = Bt + (size_t)(n0 + row) * ldb + k0 + lcol;
            __builtin_amdgcn_global_load_lds(
                (const __attribute__((address_space(1))) void*)ga,
                (__attribute__((address_space(3))) void*)(As + c * 512), 16, 0, 0);
            __builtin_amdgcn_global_load_lds(
                (const __attribute__((address_space(1))) void*)gb,
                (__attribute__((address_space(3))) void*)(Bs + c * 512), 16, 0, 0);
        }
        __syncthreads();
        bf16x8 af[4], bfv[4];
        #pragma unroll
        for (int i = 0; i < 4; i++)
            af[i] = *(const bf16x8*)(As + (wr * 64 + i * 16 + fm) * 32 + fk);
        #pragma unroll
        for (int j = 0; j < 4; j++)
            bfv[j] = *(const bf16x8*)(Bs + (wc * 64 + j * 16 + fm) * 32 + fk);
        #pragma unroll
        for (int i = 0; i < 4; i++)
            #pragma unroll
            for (int j = 0; j < 4; j++)
                acc[i][j] = __builtin_amdgcn_mfma_f32_16x16x32_bf16(
                    af[i], bfv[j], acc[i][j], 0, 0, 0);
        __syncthreads();
    }

    #pragma unroll
    for (int i = 0; i < 4; i++) {
        int mbase = m0 + wr * 64 + i * 16 + (lane >> 4) * 4;
        #pragma unroll
        for (int j = 0; j < 4; j++) {
            int col = n0 + wc * 64 + j * 16 + (lane & 15);
            float bv = bias[col];
            #pragma unroll
            for (int r = 0; r < 4; r++) {
                int row = mbase + r;
                float v = acc[i][j][r] + bv;
                if constexpr (EPI == 0) {
                    Cb[(size_t)row * ldc + col] = (bf16)v;
                } else if constexpr (EPI == 1) {
                    v = 0.5f * v * (1.0f + erff(v * 0.70710678118654752f));
                    Cb[(size_t)row * ldc + col] = (bf16)v;
                } else if constexpr (EPI == 2) {
                    float g  = (float)gate[(size_t)row * gld + col];
                    float sg = 1.0f / (1.0f + expf(-g));
                    v = (res[(size_t)row * DD + col] + sg * v) * mask[row];
                    Cf[(size_t)row * ldc + col] = v;
                } else {
                    v = (res[(size_t)row * DD + col] + v) * mask[row];
                    Cf[(size_t)row * ldc + col] = v;
                }
            }
        }
    }
}

// ---------------------------------------------------------------- dwconv (bf16 in, bf16 out into cat)
template<int KW>
__global__ __launch_bounds__(256) void dwconv_k(
    const bf16* __restrict__ x, const float* __restrict__ w,
    const float* __restrict__ bias, bf16* __restrict__ out, int coff)
{
    int idx = blockIdx.x * 256 + threadIdx.x;   // < MROWS*DD
    int cL  = idx & (DD - 1);
    int row = idx >> 10;
    int t   = row & (TT - 1);
    float acc = bias[cL];
    #pragma unroll
    for (int i = 0; i < KW; i++) {
        int tt = t - (KW - 1) + i;
        if (tt >= 0)
            acc = fmaf(w[cL * KW + i], (float)x[(size_t)(row - (KW - 1) + i) * DD + cL], acc);
    }
    out[(size_t)row * CATD + coff + cL] = (bf16)acc;
}

// ---------------------------------------------------------------- attention
__device__ __forceinline__ float phi_f(float x) {
    return x > 0.f ? x + 1.f : expf(x);   // elu(x)+1
}

__global__ __launch_bounds__(64) void attn_sums(
    const bf16* __restrict__ proj, const float* __restrict__ mask,
    float* __restrict__ kvsum, float* __restrict__ kssum)
{
    int blk = blockIdx.x;              // bh*NCH + c
    int c  = blk & (NCH - 1);
    int bh = blk >> 4;
    int b  = bh >> 4, hh = bh & (HH - 1);
    int lane = threadIdx.x;
    int e = lane & 31, d0 = (lane >> 5) * 16;
    __shared__ float sk[32], sv[32];
    float kv[16], ksl[16];
    #pragma unroll
    for (int j = 0; j < 16; j++) { kv[j] = 0.f; ksl[j] = 0.f; }
    int rbase = b * TT + c * CHUNK;
    for (int t = 0; t < CHUNK; t++) {
        int row = rbase + t;
        float m = mask[row];
        if (lane < 32)
            sk[lane] = phi_f((float)proj[(size_t)row * NPROJ + DD + INNERD + hh * 32 + lane]) * m;
        else
            sv[lane - 32] = (float)proj[(size_t)row * NPROJ + DD + 2 * INNERD + hh * 32 + (lane - 32)] * m;
        __syncthreads();
        float ve = sv[e];
        #pragma unroll
        for (int j = 0; j < 16; j++) {
            float kval = sk[d0 + j];
            kv[j] = fmaf(kval, ve, kv[j]);
            ksl[j] += kval;
        }
        __syncthreads();
    }
    size_t base = (size_t)blk * 1024;
    #pragma unroll
    for (int j = 0; j < 16; j++)
        kvsum[base + (size_t)(d0 + j) * 32 + e] = kv[j];
    if (e == 0) {
        #pragma unroll
        for (int j = 0; j < 16; j++)
            kssum[blk * 32 + d0 + j] = ksl[j];
    }
}

__global__ __launch_bounds__(256) void attn_prefix(
    const float* __restrict__ kvsum, const float* __restrict__ kssum,
    float* __restrict__ kvpref, float* __restrict__ kspref)
{
    int bh = blockIdx.x;
    int tid = threadIdx.x;
    float run[4] = {0.f, 0.f, 0.f, 0.f};
    for (int c = 0; c < NCH; c++) {
        size_t base = (size_t)(bh * NCH + c) * 1024 + tid * 4;
        #pragma unroll
        for (int q = 0; q < 4; q++) {
            kvpref[base + q] = run[q];
            run[q] += kvsum[base + q];
        }
    }
    if (tid < 32) {
        float r = 0.f;
        for (int c = 0; c < NCH; c++) {
            kspref[(bh * NCH + c) * 32 + tid] = r;
            r += kssum[(bh * NCH + c) * 32 + tid];
        }
    }
}

__global__ __launch_bounds__(64) void attn_scan(
    const bf16* __restrict__ proj, const float* __restrict__ mask,
    const float* __restrict__ kvpref, const float* __restrict__ kspref,
    bf16* __restrict__ attn_out)
{
    int blk = blockIdx.x;
    int c  = blk & (NCH - 1);
    int bh = blk >> 4;
    int b  = bh >> 4, hh = bh & (HH - 1);
    int lane = threadIdx.x;
    int e = lane & 31, d0 = (lane >> 5) * 16;
    __shared__ float sq[32], sk[32], sv[32];
    float kv[16], ksl[16];
    size_t base = (size_t)blk * 1024;
    #pragma unroll
    for (int j = 0; j < 16; j++) kv[j] = kvpref[base + (size_t)(d0 + j) * 32 + e];
    #pragma unroll
    for (int j = 0; j < 16; j++) ksl[j] = kspref[blk * 32 + d0 + j];
    int rbase = b * TT + c * CHUNK;
    for (int t = 0; t < CHUNK; t++) {
        int row = rbase + t;
        float m = mask[row];
        if (lane < 32) {
            sq[lane] = phi_f((float)proj[(size_t)row * NPROJ + DD + hh * 32 + lane]) * m;
            sk[lane] = phi_f((float)proj[(size_t)row * NPROJ + DD + INNERD + hh * 32 + lane]) * m;
        } else {
            sv[lane - 32] = (float)proj[(size_t)row * NPROJ + DD + 2 * INNERD + hh * 32 + (lane - 32)] * m;
        }
        __syncthreads();
        float ve = sv[e];
        float num = 0.f, den = 0.f;
        #pragma unroll
        for (int j = 0; j < 16; j++) {
            float kval = sk[d0 + j], qval = sq[d0 + j];
            kv[j]  = fmaf(kval, ve, kv[j]);   // inclusive cumsum
            ksl[j] += kval;
            num = fmaf(qval, kv[j],  num);
            den = fmaf(qval, ksl[j], den);
        }
        num += __shfl_xor(num, 32, 64);
        den += __shfl_xor(den, 32, 64);
        if (lane < 32)
            attn_out[(size_t)row * INNERD + hh * 32 + e] = (bf16)(num / (den + 1e-6f) * m);
        __syncthreads();
    }
}

// ---------------------------------------------------------------- launch
extern "C" void kernel_launch(void* const* d_in, const int* in_sizes, int n_in,
                              void* d_out, int out_size, void* d_ws, size_t ws_size,
                              hipStream_t stream)
{
    const float* inputs = (const float*)d_in[0];
    const float* mask   = (const float*)d_in[1];
    const float* ln1_g  = (const float*)d_in[2];
    const float* ln1_b  = (const float*)d_in[3];
    const float* W_in   = (const float*)d_in[4];
    const float* b_in   = (const float*)d_in[5];
    const float* W_c    = (const float*)d_in[6];
    const float* b_c    = (const float*)d_in[7];
    const float* w_t    = (const float*)d_in[8];
    const float* b_t    = (const float*)d_in[9];
    const float* w_p    = (const float*)d_in[10];
    const float* b_p    = (const float*)d_in[11];
    const float* W_mix  = (const float*)d_in[12];
    const float* b_mix  = (const float*)d_in[13];
    const float* ln2_g  = (const float*)d_in[14];
    const float* ln2_b  = (const float*)d_in[15];
    const float* W1     = (const float*)d_in[16];
    const float* b1     = (const float*)d_in[17];
    const float* W2     = (const float*)d_in[18];
    const float* b2     = (const float*)d_in[19];
    float* out = (float*)d_out;

    // workspace layout (bytes). ffn1 aliases [normed|proj|attn]:
    // 4096*4096 bf16 == 4096*(1024+2560+512) bf16 exactly.
    char* p = (char*)d_ws;
    bf16* normed = (bf16*)p;  p += (size_t)MROWS * DD * 2;
    bf16* proj   = (bf16*)p;  p += (size_t)MROWS * NPROJ * 2;
    bf16* attnb  = (bf16*)p;  p += (size_t)MROWS * INNERD * 2;
    bf16* cat    = (bf16*)p;  p += (size_t)MROWS * CATD * 2;
    float* out1  = (float*)p; p += (size_t)MROWS * DD * 4;
    bf16* hbuf   = (bf16*)p;  p += (size_t)MROWS * DD * 2;
    float* kvsum = (float*)p; p += (size_t)512 * 1024 * 4;
    float* kvpref= (float*)p; p += (size_t)512 * 1024 * 4;
    float* kssum = (float*)p; p += (size_t)512 * 32 * 4;
    float* kspref= (float*)p; p += (size_t)512 * 32 * 4;
    bf16* wt_in  = (bf16*)p;  p += (size_t)NPROJ * DD * 2;
    bf16* wt_c   = (bf16*)p;  p += (size_t)DD * INNERD * 2;
    bf16* wt_mix = (bf16*)p;  p += (size_t)DD * CATD * 2;
    bf16* wt1    = (bf16*)p;  p += (size_t)FFD * DD * 2;
    bf16* wt2    = (bf16*)p;  p += (size_t)DD * FFD * 2;
    bf16* ffn1   = (bf16*)d_ws;   // alias

    // 0. weight transposes fp32(K,N) -> bf16(N,K)
    transpose_cvt<<<dim3(NPROJ/32, DD/32),   256, 0, stream>>>(W_in,  wt_in,  DD,     NPROJ);
    transpose_cvt<<<dim3(DD/32,    INNERD/32),256, 0, stream>>>(W_c,   wt_c,   INNERD, DD);
    transpose_cvt<<<dim3(DD/32,    CATD/32), 256, 0, stream>>>(W_mix, wt_mix, CATD,   DD);
    transpose_cvt<<<dim3(FFD/32,   DD/32),   256, 0, stream>>>(W1,    wt1,    DD,     FFD);
    transpose_cvt<<<dim3(DD/32,    FFD/32),  256, 0, stream>>>(W2,    wt2,    FFD,    DD);

    // 1. LN1 -> bf16
    layernorm_k<<<MROWS, 256, 0, stream>>>(inputs, ln1_g, ln1_b, normed);
    // 2. proj = normed @ W_in + b_in (bf16 out)
    gemm_mfma<0><<<dim3(NPROJ/128, MROWS/128), 256, 0, stream>>>(
        normed, DD, wt_in, DD, b_in, nullptr, proj, NPROJ, DD, nullptr, 0, nullptr, nullptr);
    // 3. chunked causal linear attention -> attnb (M x 512, bf16)
    attn_sums  <<<32 * NCH, 64, 0, stream>>>(proj, mask, kvsum, kssum);
    attn_prefix<<<32, 256, 0, stream>>>(kvsum, kssum, kvpref, kspref);
    attn_scan  <<<32 * NCH, 64, 0, stream>>>(proj, mask, kvpref, kspref, attnb);
    // 4. depthwise causal convs -> cat[:,D:2D], cat[:,2D:3D]
    dwconv_k<3> <<<MROWS * DD / 256, 256, 0, stream>>>(normed, w_t, b_t, cat, DD);
    dwconv_k<15><<<MROWS * DD / 256, 256, 0, stream>>>(normed, w_p, b_p, cat, 2 * DD);
    // 5. cat[:,0:D] = attnb @ W_c + b_c (bf16 out)
    gemm_mfma<0><<<dim3(DD/128, MROWS/128), 256, 0, stream>>>(
        attnb, INNERD, wt_c, INNERD, b_c, nullptr, cat, CATD, INNERD, nullptr, 0, nullptr, nullptr);
    // 6. out1 = (inputs + sigmoid(gate) * (cat @ W_mix + b_mix)) * mask  (fp32)
    gemm_mfma<2><<<dim3(DD/128, MROWS/128), 256, 0, stream>>>(
        cat, CATD, wt_mix, CATD, b_mix, out1, nullptr, DD, CATD, proj, NPROJ, inputs, mask);
    // 7. LN2 -> bf16
    layernorm_k<<<MROWS, 256, 0, stream>>>(out1, ln2_g, ln2_b, hbuf);
    // 8. ffn1 = gelu(hbuf @ W1 + b1) (bf16 out; aliases dead normed/proj/attnb)
    gemm_mfma<1><<<dim3(FFD/128, MROWS/128), 256, 0, stream>>>(
        hbuf, DD, wt1, DD, b1, nullptr, ffn1, FFD, DD, nullptr, 0, nullptr, nullptr);
    // 9. out = (out1 + ffn1 @ W2 + b2) * mask (fp32)
    gemm_mfma<3><<<dim3(DD/128, MROWS/128), 256, 0, stream>>>(
        ffn1, FFD, wt2, FFD, b2, out, nullptr, DD, FFD, nullptr, 0, out1, mask);
}

// Round 3
// 570.482 us; speedup vs baseline: 3.8279x; 1.2563x over previous
//
#include <hip/hip_runtime.h>
#include <math.h>

#define BB 2
#define TT 2048
#define DD 1024
#define HH 16
#define INNERD 512
#define FFD 4096
#define NPROJ 2560     // D + 3*INNER
#define CATD 3072      // 3*D
#define MROWS (BB*TT)  // 4096
#define CHUNK 64
#define NCH (TT/CHUNK) // 32
#define BH 32          // B*H

typedef __bf16 bf16;
typedef __attribute__((ext_vector_type(8))) __bf16 bf16x8;
typedef __attribute__((ext_vector_type(4))) float f32x4;

// ---------------------------------------------------------------- layernorm -> bf16
__global__ __launch_bounds__(256) void layernorm_k(
    const float* __restrict__ x, const float* __restrict__ g,
    const float* __restrict__ bta, bf16* __restrict__ y)
{
    int row = blockIdx.x;
    const float* xr = x + (size_t)row * DD;
    float s = 0.f, s2 = 0.f;
    for (int i = threadIdx.x; i < DD; i += 256) {
        float v = xr[i]; s += v; s2 += v * v;
    }
    #pragma unroll
    for (int off = 32; off > 0; off >>= 1) {
        s  += __shfl_xor(s,  off, 64);
        s2 += __shfl_xor(s2, off, 64);
    }
    __shared__ float rs[4], rs2[4];
    int wid = threadIdx.x >> 6;
    if ((threadIdx.x & 63) == 0) { rs[wid] = s; rs2[wid] = s2; }
    __syncthreads();
    s  = rs[0] + rs[1] + rs[2] + rs[3];
    s2 = rs2[0] + rs2[1] + rs2[2] + rs2[3];
    float mean = s * (1.0f / DD);
    float var  = s2 * (1.0f / DD) - mean * mean;
    float rstd = rsqrtf(var + 1e-5f);
    bf16* yr = y + (size_t)row * DD;
    for (int i = threadIdx.x; i < DD; i += 256)
        yr[i] = (bf16)((xr[i] - mean) * rstd * g[i] + bta[i]);
}

// ---------------------------------------------------------------- weight transpose fp32(K,N) -> bf16(N,K)
__global__ __launch_bounds__(256) void transpose_cvt(
    const float* __restrict__ W, bf16* __restrict__ Wt, int Kd, int Nd)
{
    __shared__ float t[32][33];
    int nb = blockIdx.x * 32, kb = blockIdx.y * 32;
    int tx = threadIdx.x & 31, ty = threadIdx.x >> 5;   // 32 x 8
    #pragma unroll
    for (int r = 0; r < 32; r += 8)
        t[ty + r][tx] = W[(size_t)(kb + ty + r) * Nd + nb + tx];
    __syncthreads();
    #pragma unroll
    for (int r = 0; r < 32; r += 8)
        Wt[(size_t)(nb + ty + r) * Kd + kb + tx] = (bf16)t[tx][ty + r];
}

// ---------------------------------------------------------------- MFMA GEMM
// C = epilogue(A[M,K] @ Bt[N,K]^T + bias)
// EPI 0: plain -> bf16      EPI 1: exact gelu -> bf16
// EPI 2: (res + sigmoid(gate)*v)*mask -> fp32
// EPI 3: (res + v)*mask -> fp32
template<int EPI>
__global__ __launch_bounds__(256) void gemm_mfma(
    const bf16* __restrict__ A,  int lda,
    const bf16* __restrict__ Bt, int ldb,
    const float* __restrict__ bias,
    float* __restrict__ Cf, bf16* __restrict__ Cb, int ldc,
    int K,
    const bf16* __restrict__ gate, int gld,
    const float* __restrict__ res,
    const float* __restrict__ mask)
{
    __shared__ bf16 As[128 * 32];
    __shared__ bf16 Bs[128 * 32];
    const int tid  = threadIdx.x;
    const int wave = tid >> 6, lane = tid & 63;
    const int m0 = blockIdx.y * 128, n0 = blockIdx.x * 128;
    const int wr = wave >> 1, wc = wave & 1;
    const int lrow = lane >> 2;          // staging row within 16-row chunk
    const int lcol = (lane & 3) * 8;     // staging k offset (elems)
    const int fm = lane & 15;            // fragment m/n within 16-tile
    const int fk = (lane >> 4) * 8;      // fragment k offset

    f32x4 acc[4][4];
    #pragma unroll
    for (int i = 0; i < 4; i++)
        #pragma unroll
        for (int j = 0; j < 4; j++)
            acc[i][j] = (f32x4){0.f, 0.f, 0.f, 0.f};

    for (int k0 = 0; k0 < K; k0 += 32) {
        #pragma unroll
        for (int r = 0; r < 2; r++) {
            int c = r * 4 + wave;                 // 16-row chunk index 0..7
            int row = c * 16 + lrow;
            const bf16* ga = A  + (size_t)(m0 + row) * lda + k0 + lcol;
            const bf16* gb = Bt + (size_t)(n0 + row) * ldb + k0 + lcol;
            __builtin_amdgcn_global_load_lds(
                (const __attribute__((address_space(1))) void*)ga,
                (__attribute__((address_space(3))) void*)(As + c * 512), 16, 0, 0);
            __builtin_amdgcn_global_load_lds(
                (const __attribute__((address_space(1))) void*)gb,
                (__attribute__((address_space(3))) void*)(Bs + c * 512), 16, 0, 0);
        }
        __syncthreads();
        bf16x8 af[4], bfv[4];
        #pragma unroll
        for (int i = 0; i < 4; i++)
            af[i] = *(const bf16x8*)(As + (wr * 64 + i * 16 + fm) * 32 + fk);
        #pragma unroll
        for (int j = 0; j < 4; j++)
            bfv[j] = *(const bf16x8*)(Bs + (wc * 64 + j * 16 + fm) * 32 + fk);
        #pragma unroll
        for (int i = 0; i < 4; i++)
            #pragma unroll
            for (int j = 0; j < 4; j++)
                acc[i][j] = __builtin_amdgcn_mfma_f32_16x16x32_bf16(
                    af[i], bfv[j], acc[i][j], 0, 0, 0);
        __syncthreads();
    }

    #pragma unroll
    for (int i = 0; i < 4; i++) {
        int mbase = m0 + wr * 64 + i * 16 + (lane >> 4) * 4;
        #pragma unroll
        for (int j = 0; j < 4; j++) {
            int col = n0 + wc * 64 + j * 16 + (lane & 15);
            float bv = bias[col];
            #pragma unroll
            for (int r = 0; r < 4; r++) {
                int row = mbase + r;
                float v = acc[i][j][r] + bv;
                if constexpr (EPI == 0) {
                    Cb[(size_t)row * ldc + col] = (bf16)v;
                } else if constexpr (EPI == 1) {
                    v = 0.5f * v * (1.0f + erff(v * 0.70710678118654752f));
                    Cb[(size_t)row * ldc + col] = (bf16)v;
                } else if constexpr (EPI == 2) {
                    float g  = (float)gate[(size_t)row * gld + col];
                    float sg = 1.0f / (1.0f + expf(-g));
                    v = (res[(size_t)row * DD + col] + sg * v) * mask[row];
                    Cf[(size_t)row * ldc + col] = v;
                } else {
                    v = (res[(size_t)row * DD + col] + v) * mask[row];
                    Cf[(size_t)row * ldc + col] = v;
                }
            }
        }
    }
}

// ---------------------------------------------------------------- dwconv (bf16 in, bf16 out into cat)
template<int KW>
__global__ __launch_bounds__(256) void dwconv_k(
    const bf16* __restrict__ x, const float* __restrict__ w,
    const float* __restrict__ bias, bf16* __restrict__ out, int coff)
{
    int idx = blockIdx.x * 256 + threadIdx.x;   // < MROWS*DD
    int cL  = idx & (DD - 1);
    int row = idx >> 10;
    int t   = row & (TT - 1);
    float acc = bias[cL];
    #pragma unroll
    for (int i = 0; i < KW; i++) {
        int tt = t - (KW - 1) + i;
        if (tt >= 0)
            acc = fmaf(w[cL * KW + i], (float)x[(size_t)(row - (KW - 1) + i) * DD + cL], acc);
    }
    out[(size_t)row * CATD + coff + cL] = (bf16)acc;
}

// ---------------------------------------------------------------- attention
__device__ __forceinline__ float phi_f(float x) {
    return x > 0.f ? x + 1.f : expf(x);   // elu(x)+1
}

// Phase A: per-(b,h,chunk) local sums, LDS-resident. One wave/block, lane==t.
__global__ __launch_bounds__(64) void attn_sums(
    const bf16* __restrict__ proj, const float* __restrict__ mask,
    float* __restrict__ kvsum, float* __restrict__ kssum)
{
    int blk = blockIdx.x;              // bh*NCH + c
    int c  = blk & (NCH - 1);
    int bh = blk >> 5;
    int b  = bh >> 4, hh = bh & (HH - 1);
    int lane = threadIdx.x;
    __shared__ float ks[CHUNK][32], vs[CHUNK][32];
    int row0 = b * TT + c * CHUNK;
    {   // preload: lane t loads its whole row vectorized, applies phi/mask
        int row = row0 + lane;
        float m = mask[row];
        const bf16* kp = proj + (size_t)row * NPROJ + DD + INNERD + hh * 32;
        const bf16* vp = kp + INNERD;
        #pragma unroll
        for (int s = 0; s < 4; s++) {
            bf16x8 k8 = *(const bf16x8*)(kp + s * 8);
            bf16x8 v8 = *(const bf16x8*)(vp + s * 8);
            #pragma unroll
            for (int q = 0; q < 8; q++) {
                ks[lane][s * 8 + q] = phi_f((float)k8[q]) * m;
                vs[lane][s * 8 + q] = (float)v8[q] * m;
            }
        }
    }
    __syncthreads();
    int e = lane & 31, d0 = (lane >> 5) * 16;
    float kv[16], ksl[16];
    #pragma unroll
    for (int j = 0; j < 16; j++) { kv[j] = 0.f; ksl[j] = 0.f; }
    for (int t = 0; t < CHUNK; t++) {
        float ve = vs[t][e];
        f32x4 kr[4];
        #pragma unroll
        for (int s = 0; s < 4; s++) kr[s] = *(const f32x4*)&ks[t][d0 + s * 4];
        #pragma unroll
        for (int j = 0; j < 16; j++) {
            float kval = kr[j >> 2][j & 3];
            kv[j] = fmaf(kval, ve, kv[j]);
            ksl[j] += kval;
        }
    }
    size_t base = (size_t)blk * 1024;
    #pragma unroll
    for (int j = 0; j < 16; j++)
        kvsum[base + (size_t)(d0 + j) * 32 + e] = kv[j];
    if (e == 0) {
        #pragma unroll
        for (int j = 0; j < 16; j++)
            kssum[blk * 32 + d0 + j] = ksl[j];
    }
}

// Phase B: exclusive prefix over chunks, per (b,h).
__global__ __launch_bounds__(256) void attn_prefix(
    const float* __restrict__ kvsum, const float* __restrict__ kssum,
    float* __restrict__ kvpref, float* __restrict__ kspref)
{
    int bh = blockIdx.x;
    int tid = threadIdx.x;
    float run[4] = {0.f, 0.f, 0.f, 0.f};
    for (int c = 0; c < NCH; c++) {
        size_t base = (size_t)(bh * NCH + c) * 1024 + tid * 4;
        #pragma unroll
        for (int q = 0; q < 4; q++) {
            kvpref[base + q] = run[q];
            run[q] += kvsum[base + q];
        }
    }
    if (tid < 32) {
        float r = 0.f;
        for (int c = 0; c < NCH; c++) {
            kspref[(bh * NCH + c) * 32 + tid] = r;
            r += kssum[(bh * NCH + c) * 32 + tid];
        }
    }
}

// Phase C: in-chunk scan, LDS-resident.
__global__ __launch_bounds__(64) void attn_scan(
    const bf16* __restrict__ proj, const float* __restrict__ mask,
    const float* __restrict__ kvpref, const float* __restrict__ kspref,
    bf16* __restrict__ attn_out)
{
    int blk = blockIdx.x;
    int c  = blk & (NCH - 1);
    int bh = blk >> 5;
    int b  = bh >> 4, hh = bh & (HH - 1);
    int lane = threadIdx.x;
    __shared__ float qs[CHUNK][32], ks[CHUNK][32], vs[CHUNK][32];
    __shared__ float ms[CHUNK];
    int row0 = b * TT + c * CHUNK;
    {
        int row = row0 + lane;
        float m = mask[row];
        ms[lane] = m;
        const bf16* qp = proj + (size_t)row * NPROJ + DD + hh * 32;
        const bf16* kp = qp + INNERD;
        const bf16* vp = kp + INNERD;
        #pragma unroll
        for (int s = 0; s < 4; s++) {
            bf16x8 q8 = *(const bf16x8*)(qp + s * 8);
            bf16x8 k8 = *(const bf16x8*)(kp + s * 8);
            bf16x8 v8 = *(const bf16x8*)(vp + s * 8);
            #pragma unroll
            for (int q = 0; q < 8; q++) {
                qs[lane][s * 8 + q] = phi_f((float)q8[q]) * m;
                ks[lane][s * 8 + q] = phi_f((float)k8[q]) * m;
                vs[lane][s * 8 + q] = (float)v8[q] * m;
            }
        }
    }
    int e = lane & 31, d0 = (lane >> 5) * 16;
    float kv[16], ksl[16];
    size_t base = (size_t)blk * 1024;
    #pragma unroll
    for (int j = 0; j < 16; j++) kv[j] = kvpref[base + (size_t)(d0 + j) * 32 + e];
    #pragma unroll
    for (int j = 0; j < 16; j++) ksl[j] = kspref[blk * 32 + d0 + j];
    __syncthreads();
    for (int t = 0; t < CHUNK; t++) {
        float ve = vs[t][e];
        f32x4 kr[4], qr[4];
        #pragma unroll
        for (int s = 0; s < 4; s++) kr[s] = *(const f32x4*)&ks[t][d0 + s * 4];
        #pragma unroll
        for (int s = 0; s < 4; s++) qr[s] = *(const f32x4*)&qs[t][d0 + s * 4];
        float num0 = 0.f, num1 = 0.f, den0 = 0.f, den1 = 0.f;
        #pragma unroll
        for (int j = 0; j < 16; j++) {
            float kval = kr[j >> 2][j & 3], qval = qr[j >> 2][j & 3];
            kv[j]  = fmaf(kval, ve, kv[j]);   // inclusive cumsum
            ksl[j] += kval;
            if (j & 1) { num1 = fmaf(qval, kv[j], num1); den1 = fmaf(qval, ksl[j], den1); }
            else       { num0 = fmaf(qval, kv[j], num0); den0 = fmaf(qval, ksl[j], den0); }
        }
        float num = num0 + num1, den = den0 + den1;
        num += __shfl_xor(num, 32, 64);
        den += __shfl_xor(den, 32, 64);
        if (lane < 32)
            attn_out[(size_t)(row0 + t) * INNERD + hh * 32 + e] =
                (bf16)(num / (den + 1e-6f) * ms[t]);
    }
}

// ---------------------------------------------------------------- launch
extern "C" void kernel_launch(void* const* d_in, const int* in_sizes, int n_in,
                              void* d_out, int out_size, void* d_ws, size_t ws_size,
                              hipStream_t stream)
{
    const float* inputs = (const float*)d_in[0];
    const float* mask   = (const float*)d_in[1];
    const float* ln1_g  = (const float*)d_in[2];
    const float* ln1_b  = (const float*)d_in[3];
    const float* W_in   = (const float*)d_in[4];
    const float* b_in   = (const float*)d_in[5];
    const float* W_c    = (const float*)d_in[6];
    const float* b_c    = (const float*)d_in[7];
    const float* w_t    = (const float*)d_in[8];
    const float* b_t    = (const float*)d_in[9];
    const float* w_p    = (const float*)d_in[10];
    const float* b_p    = (const float*)d_in[11];
    const float* W_mix  = (const float*)d_in[12];
    const float* b_mix  = (const float*)d_in[13];
    const float* ln2_g  = (const float*)d_in[14];
    const float* ln2_b  = (const float*)d_in[15];
    const float* W1     = (const float*)d_in[16];
    const float* b1     = (const float*)d_in[17];
    const float* W2     = (const float*)d_in[18];
    const float* b2     = (const float*)d_in[19];
    float* out = (float*)d_out;

    // workspace layout (bytes). ffn1 aliases [normed|proj|attnb]:
    // 4096*4096 bf16 == 4096*(1024+2560+512) bf16 exactly.
    // kv scratch aliases out1 (dead until GEMM-6): 8.25 MB <= 16 MB.
    char* p = (char*)d_ws;
    bf16* normed = (bf16*)p;  p += (size_t)MROWS * DD * 2;
    bf16* proj   = (bf16*)p;  p += (size_t)MROWS * NPROJ * 2;
    bf16* attnb  = (bf16*)p;  p += (size_t)MROWS * INNERD * 2;
    bf16* cat    = (bf16*)p;  p += (size_t)MROWS * CATD * 2;
    float* out1  = (float*)p; p += (size_t)MROWS * DD * 4;
    bf16* hbuf   = (bf16*)p;  p += (size_t)MROWS * DD * 2;
    bf16* wt_in  = (bf16*)p;  p += (size_t)NPROJ * DD * 2;
    bf16* wt_c   = (bf16*)p;  p += (size_t)DD * INNERD * 2;
    bf16* wt_mix = (bf16*)p;  p += (size_t)DD * CATD * 2;
    bf16* wt1    = (bf16*)p;  p += (size_t)FFD * DD * 2;
    bf16* wt2    = (bf16*)p;  p += (size_t)DD * FFD * 2;
    bf16* ffn1   = (bf16*)d_ws;                  // alias [normed|proj|attnb]
    float* kvsum = out1;                         // alias out1 region
    float* kvpref= kvsum  + (size_t)BH * NCH * 1024;
    float* kssum = kvpref + (size_t)BH * NCH * 1024;
    float* kspref= kssum  + (size_t)BH * NCH * 32;

    // 0. weight transposes fp32(K,N) -> bf16(N,K)
    transpose_cvt<<<dim3(NPROJ/32, DD/32),   256, 0, stream>>>(W_in,  wt_in,  DD,     NPROJ);
    transpose_cvt<<<dim3(DD/32,    INNERD/32),256, 0, stream>>>(W_c,   wt_c,   INNERD, DD);
    transpose_cvt<<<dim3(DD/32,    CATD/32), 256, 0, stream>>>(W_mix, wt_mix, CATD,   DD);
    transpose_cvt<<<dim3(FFD/32,   DD/32),   256, 0, stream>>>(W1,    wt1,    DD,     FFD);
    transpose_cvt<<<dim3(DD/32,    FFD/32),  256, 0, stream>>>(W2,    wt2,    FFD,    DD);

    // 1. LN1 -> bf16
    layernorm_k<<<MROWS, 256, 0, stream>>>(inputs, ln1_g, ln1_b, normed);
    // 2. proj = normed @ W_in + b_in (bf16 out)
    gemm_mfma<0><<<dim3(NPROJ/128, MROWS/128), 256, 0, stream>>>(
        normed, DD, wt_in, DD, b_in, nullptr, proj, NPROJ, DD, nullptr, 0, nullptr, nullptr);
    // 3. chunked causal linear attention -> attnb (M x 512, bf16)
    attn_sums  <<<BH * NCH, 64, 0, stream>>>(proj, mask, kvsum, kssum);
    attn_prefix<<<BH, 256, 0, stream>>>(kvsum, kssum, kvpref, kspref);
    attn_scan  <<<BH * NCH, 64, 0, stream>>>(proj, mask, kvpref, kspref, attnb);
    // 4. depthwise causal convs -> cat[:,D:2D], cat[:,2D:3D]
    dwconv_k<3> <<<MROWS * DD / 256, 256, 0, stream>>>(normed, w_t, b_t, cat, DD);
    dwconv_k<15><<<MROWS * DD / 256, 256, 0, stream>>>(normed, w_p, b_p, cat, 2 * DD);
    // 5. cat[:,0:D] = attnb @ W_c + b_c (bf16 out)
    gemm_mfma<0><<<dim3(DD/128, MROWS/128), 256, 0, stream>>>(
        attnb, INNERD, wt_c, INNERD, b_c, nullptr, cat, CATD, INNERD, nullptr, 0, nullptr, nullptr);
    // 6. out1 = (inputs + sigmoid(gate) * (cat @ W_mix + b_mix)) * mask  (fp32)
    gemm_mfma<2><<<dim3(DD/128, MROWS/128), 256, 0, stream>>>(
        cat, CATD, wt_mix, CATD, b_mix, out1, nullptr, DD, CATD, proj, NPROJ, inputs, mask);
    // 7. LN2 -> bf16
    layernorm_k<<<MROWS, 256, 0, stream>>>(out1, ln2_g, ln2_b, hbuf);
    // 8. ffn1 = gelu(hbuf @ W1 + b1) (bf16 out; aliases dead normed/proj/attnb)
    gemm_mfma<1><<<dim3(FFD/128, MROWS/128), 256, 0, stream>>>(
        hbuf, DD, wt1, DD, b1, nullptr, ffn1, FFD, DD, nullptr, 0, nullptr, nullptr);
    // 9. out = (out1 + ffn1 @ W2 + b2) * mask (fp32)
    gemm_mfma<3><<<dim3(DD/128, MROWS/128), 256, 0, stream>>>(
        ffn1, FFD, wt2, FFD, b2, out, nullptr, DD, FFD, nullptr, 0, out1, mask);
}

// Round 4
// 540.170 us; speedup vs baseline: 4.0427x; 1.0561x over previous
//
#include <hip/hip_runtime.h>
#include <math.h>

#define BB 2
#define TT 2048
#define DD 1024
#define HH 16
#define INNERD 512
#define FFD 4096
#define NPROJ 2560     // D + 3*INNER
#define CATD 3072      // 3*D
#define MROWS (BB*TT)  // 4096
#define CHUNK 64
#define NCH (TT/CHUNK) // 32
#define BH 32          // B*H

typedef __bf16 bf16;
typedef __attribute__((ext_vector_type(8))) __bf16 bf16x8;
typedef __attribute__((ext_vector_type(4))) __bf16 bf16x4;
typedef __attribute__((ext_vector_type(4))) float f32x4;

// ---------------------------------------------------------------- layernorm -> bf16 (vectorized)
__global__ __launch_bounds__(256) void layernorm_k(
    const float* __restrict__ x, const float* __restrict__ g,
    const float* __restrict__ bta, bf16* __restrict__ y)
{
    int row = blockIdx.x, tid = threadIdx.x;
    f32x4 xv = ((const f32x4*)(x + (size_t)row * DD))[tid];
    float s = xv[0] + xv[1] + xv[2] + xv[3];
    float s2 = xv[0]*xv[0] + xv[1]*xv[1] + xv[2]*xv[2] + xv[3]*xv[3];
    #pragma unroll
    for (int off = 32; off > 0; off >>= 1) {
        s  += __shfl_xor(s,  off, 64);
        s2 += __shfl_xor(s2, off, 64);
    }
    __shared__ float rs[4], rs2[4];
    int wid = tid >> 6;
    if ((tid & 63) == 0) { rs[wid] = s; rs2[wid] = s2; }
    __syncthreads();
    s  = rs[0] + rs[1] + rs[2] + rs[3];
    s2 = rs2[0] + rs2[1] + rs2[2] + rs2[3];
    float mean = s * (1.0f / DD);
    float var  = s2 * (1.0f / DD) - mean * mean;
    float rstd = rsqrtf(var + 1e-5f);
    f32x4 gv = ((const f32x4*)g)[tid];
    f32x4 bv = ((const f32x4*)bta)[tid];
    bf16x4 o;
    #pragma unroll
    for (int q = 0; q < 4; q++)
        o[q] = (bf16)((xv[q] - mean) * rstd * gv[q] + bv[q]);
    ((bf16x4*)(y + (size_t)row * DD))[tid] = o;
}

// ---------------------------------------------------------------- weight transpose fp32(K,N) -> bf16(N,K)
__global__ __launch_bounds__(256) void transpose_cvt(
    const float* __restrict__ W, bf16* __restrict__ Wt, int Kd, int Nd)
{
    __shared__ float t[32][33];
    int nb = blockIdx.x * 32, kb = blockIdx.y * 32;
    int tx = threadIdx.x & 31, ty = threadIdx.x >> 5;   // 32 x 8
    #pragma unroll
    for (int r = 0; r < 32; r += 8)
        t[ty + r][tx] = W[(size_t)(kb + ty + r) * Nd + nb + tx];
    __syncthreads();
    #pragma unroll
    for (int r = 0; r < 32; r += 8)
        Wt[(size_t)(nb + ty + r) * Kd + kb + tx] = (bf16)t[tx][ty + r];
}

// ---------------------------------------------------------------- MFMA GEMM
// C = epilogue(A[M,koff:koff+K] @ Bt[N,koff:koff+K]^T [+ bias])
// EPI 0: +bias -> bf16   EPI 1: gelu(+bias) -> bf16
// EPI 4: fp32 atomic accumulate (no bias); koff = blockIdx.z * K
template<int EPI>
__global__ __launch_bounds__(256) void gemm_mfma(
    const bf16* __restrict__ A,  int lda,
    const bf16* __restrict__ Bt, int ldb,
    const float* __restrict__ bias,
    float* __restrict__ Cf, bf16* __restrict__ Cb, int ldc,
    int K)
{
    __shared__ bf16 As[128 * 32];
    __shared__ bf16 Bs[128 * 32];
    const int tid  = threadIdx.x;
    const int wave = tid >> 6, lane = tid & 63;
    const int m0 = blockIdx.y * 128, n0 = blockIdx.x * 128;
    const int koff = blockIdx.z * K;
    A  += koff;
    Bt += koff;
    const int wr = wave >> 1, wc = wave & 1;
    const int lrow = lane >> 2;          // staging row within 16-row chunk
    const int lcol = (lane & 3) * 8;     // staging k offset (elems)
    const int fm = lane & 15;            // fragment m/n within 16-tile
    const int fk = (lane >> 4) * 8;      // fragment k offset

    f32x4 acc[4][4];
    #pragma unroll
    for (int i = 0; i < 4; i++)
        #pragma unroll
        for (int j = 0; j < 4; j++)
            acc[i][j] = (f32x4){0.f, 0.f, 0.f, 0.f};

    for (int k0 = 0; k0 < K; k0 += 32) {
        #pragma unroll
        for (int r = 0; r < 2; r++) {
            int c = r * 4 + wave;                 // 16-row chunk index 0..7
            int row = c * 16 + lrow;
            const bf16* ga = A  + (size_t)(m0 + row) * lda + k0 + lcol;
            const bf16* gb = Bt + (size_t)(n0 + row) * ldb + k0 + lcol;
            __builtin_amdgcn_global_load_lds(
                (const __attribute__((address_space(1))) void*)ga,
                (__attribute__((address_space(3))) void*)(As + c * 512), 16, 0, 0);
            __builtin_amdgcn_global_load_lds(
                (const __attribute__((address_space(1))) void*)gb,
                (__attribute__((address_space(3))) void*)(Bs + c * 512), 16, 0, 0);
        }
        __syncthreads();
        bf16x8 af[4], bfv[4];
        #pragma unroll
        for (int i = 0; i < 4; i++)
            af[i] = *(const bf16x8*)(As + (wr * 64 + i * 16 + fm) * 32 + fk);
        #pragma unroll
        for (int j = 0; j < 4; j++)
            bfv[j] = *(const bf16x8*)(Bs + (wc * 64 + j * 16 + fm) * 32 + fk);
        #pragma unroll
        for (int i = 0; i < 4; i++)
            #pragma unroll
            for (int j = 0; j < 4; j++)
                acc[i][j] = __builtin_amdgcn_mfma_f32_16x16x32_bf16(
                    af[i], bfv[j], acc[i][j], 0, 0, 0);
        __syncthreads();
    }

    #pragma unroll
    for (int i = 0; i < 4; i++) {
        int mbase = m0 + wr * 64 + i * 16 + (lane >> 4) * 4;
        #pragma unroll
        for (int j = 0; j < 4; j++) {
            int col = n0 + wc * 64 + j * 16 + (lane & 15);
            float bv = (EPI == 4) ? 0.f : bias[col];
            #pragma unroll
            for (int r = 0; r < 4; r++) {
                int row = mbase + r;
                float v = acc[i][j][r] + bv;
                if constexpr (EPI == 0) {
                    Cb[(size_t)row * ldc + col] = (bf16)v;
                } else if constexpr (EPI == 1) {
                    v = 0.5f * v * (1.0f + erff(v * 0.70710678118654752f));
                    Cb[(size_t)row * ldc + col] = (bf16)v;
                } else {
                    unsafeAtomicAdd(&Cf[(size_t)row * ldc + col], v);
                }
            }
        }
    }
}

// ---------------------------------------------------------------- fused epilogue: W_mix gate + residual + mask, then LN2
// out1 = (res + sigmoid(gate) * (S + bias)) * mask ;  hbuf = LN(out1)
__global__ __launch_bounds__(256) void epi_mix_ln2(
    const float* __restrict__ S, const float* __restrict__ bias,
    const bf16* __restrict__ proj, const float* __restrict__ res,
    const float* __restrict__ mask,
    const float* __restrict__ g2, const float* __restrict__ b2v,
    float* __restrict__ out1, bf16* __restrict__ hbuf)
{
    int row = blockIdx.x, tid = threadIdx.x;
    float m = mask[row];
    f32x4 sv = ((const f32x4*)(S + (size_t)row * DD))[tid];
    f32x4 bv = ((const f32x4*)bias)[tid];
    bf16x4 g4 = *(const bf16x4*)(proj + (size_t)row * NPROJ + tid * 4);
    f32x4 rv = ((const f32x4*)(res + (size_t)row * DD))[tid];
    f32x4 v;
    #pragma unroll
    for (int q = 0; q < 4; q++) {
        float sg = 1.0f / (1.0f + expf(-(float)g4[q]));
        v[q] = (rv[q] + sg * (sv[q] + bv[q])) * m;
    }
    ((f32x4*)(out1 + (size_t)row * DD))[tid] = v;
    // LN2
    float s = v[0] + v[1] + v[2] + v[3];
    float s2 = v[0]*v[0] + v[1]*v[1] + v[2]*v[2] + v[3]*v[3];
    #pragma unroll
    for (int off = 32; off > 0; off >>= 1) {
        s  += __shfl_xor(s,  off, 64);
        s2 += __shfl_xor(s2, off, 64);
    }
    __shared__ float rs[4], rs2[4];
    int wid = tid >> 6;
    if ((tid & 63) == 0) { rs[wid] = s; rs2[wid] = s2; }
    __syncthreads();
    s  = rs[0] + rs[1] + rs[2] + rs[3];
    s2 = rs2[0] + rs2[1] + rs2[2] + rs2[3];
    float mean = s * (1.0f / DD);
    float var  = s2 * (1.0f / DD) - mean * mean;
    float rstd = rsqrtf(var + 1e-5f);
    f32x4 gg = ((const f32x4*)g2)[tid];
    f32x4 bb = ((const f32x4*)b2v)[tid];
    bf16x4 h;
    #pragma unroll
    for (int q = 0; q < 4; q++)
        h[q] = (bf16)((v[q] - mean) * rstd * gg[q] + bb[q]);
    ((bf16x4*)(hbuf + (size_t)row * DD))[tid] = h;
}

// ---------------------------------------------------------------- final epilogue: out = (out1 + S + b2) * mask, in-place on d_out
__global__ __launch_bounds__(256) void epi_w2(
    float* __restrict__ d_out, const float* __restrict__ out1,
    const float* __restrict__ bias, const float* __restrict__ mask)
{
    int id = blockIdx.x * 256 + threadIdx.x;    // over MROWS*DD/4
    int row = id >> 8;                          // 256 f32x4 per row
    float m = mask[row];
    f32x4 a = ((const f32x4*)d_out)[id];
    f32x4 r = ((const f32x4*)out1)[id];
    f32x4 b = ((const f32x4*)bias)[id & 255];
    f32x4 o;
    #pragma unroll
    for (int q = 0; q < 4; q++) o[q] = (r[q] + a[q] + b[q]) * m;
    ((f32x4*)d_out)[id] = o;
}

// ---------------------------------------------------------------- fused dwconv (both kernels, 2 rows/thread, vectorized)
__global__ __launch_bounds__(256) void dwconv_fused(
    const bf16* __restrict__ x,
    const float* __restrict__ w_t, const float* __restrict__ b_t,
    const float* __restrict__ w_p, const float* __restrict__ b_p,
    bf16* __restrict__ cat)
{
    int id = blockIdx.x * 256 + threadIdx.x;    // over (MROWS/2)*128
    int cg = id & 127, rp = id >> 7;
    int c0 = cg * 8;
    int row0 = rp * 2;
    int t0 = row0 & (TT - 1);
    // input window rows row0-14 .. row0+1 (16 rows), zero before batch start
    bf16x8 xw[16];
    #pragma unroll
    for (int j = 0; j < 16; j++) {
        int t = t0 - 14 + j;
        if (t >= 0)
            xw[j] = *(const bf16x8*)(x + (size_t)(row0 - 14 + j) * DD + c0);
        else
            #pragma unroll
            for (int q = 0; q < 8; q++) xw[j][q] = (bf16)0.f;
    }
    float y15[2][8], y3[2][8];
    #pragma unroll
    for (int q = 0; q < 8; q++) {
        float bp = b_p[c0 + q], bt = b_t[c0 + q];
        y15[0][q] = bp; y15[1][q] = bp;
        y3[0][q] = bt;  y3[1][q] = bt;
    }
    #pragma unroll
    for (int i = 0; i < 15; i++) {
        float wp[8];
        #pragma unroll
        for (int q = 0; q < 8; q++) wp[q] = w_p[(c0 + q) * 15 + i];
        #pragma unroll
        for (int rr = 0; rr < 2; rr++)
            #pragma unroll
            for (int q = 0; q < 8; q++)
                y15[rr][q] = fmaf(wp[q], (float)xw[rr + i][q], y15[rr][q]);
    }
    #pragma unroll
    for (int i = 0; i < 3; i++) {
        float wt[8];
        #pragma unroll
        for (int q = 0; q < 8; q++) wt[q] = w_t[(c0 + q) * 3 + i];
        #pragma unroll
        for (int rr = 0; rr < 2; rr++)
            #pragma unroll
            for (int q = 0; q < 8; q++)
                y3[rr][q] = fmaf(wt[q], (float)xw[rr + 12 + i][q], y3[rr][q]);
    }
    #pragma unroll
    for (int rr = 0; rr < 2; rr++) {
        bf16x8 o3, o15;
        #pragma unroll
        for (int q = 0; q < 8; q++) { o3[q] = (bf16)y3[rr][q]; o15[q] = (bf16)y15[rr][q]; }
        *(bf16x8*)(cat + (size_t)(row0 + rr) * CATD + DD + c0)     = o3;
        *(bf16x8*)(cat + (size_t)(row0 + rr) * CATD + 2 * DD + c0) = o15;
    }
}

// ---------------------------------------------------------------- attention
__device__ __forceinline__ float phi_f(float x) {
    return x > 0.f ? x + 1.f : expf(x);   // elu(x)+1
}

// Phase A: per-(b,h,chunk) local sums, LDS-resident. One wave/block, lane==t.
__global__ __launch_bounds__(64) void attn_sums(
    const bf16* __restrict__ proj, const float* __restrict__ mask,
    float* __restrict__ kvsum, float* __restrict__ kssum)
{
    int blk = blockIdx.x;              // bh*NCH + c
    int c  = blk & (NCH - 1);
    int bh = blk >> 5;
    int b  = bh >> 4, hh = bh & (HH - 1);
    int lane = threadIdx.x;
    __shared__ float ks[CHUNK][32], vs[CHUNK][32];
    int row0 = b * TT + c * CHUNK;
    {   // preload: lane t loads its whole row vectorized, applies phi/mask
        int row = row0 + lane;
        float m = mask[row];
        const bf16* kp = proj + (size_t)row * NPROJ + DD + INNERD + hh * 32;
        const bf16* vp = kp + INNERD;
        #pragma unroll
        for (int s = 0; s < 4; s++) {
            bf16x8 k8 = *(const bf16x8*)(kp + s * 8);
            bf16x8 v8 = *(const bf16x8*)(vp + s * 8);
            #pragma unroll
            for (int q = 0; q < 8; q++) {
                ks[lane][s * 8 + q] = phi_f((float)k8[q]) * m;
                vs[lane][s * 8 + q] = (float)v8[q] * m;
            }
        }
    }
    __syncthreads();
    int e = lane & 31, d0 = (lane >> 5) * 16;
    float kv[16], ksl[16];
    #pragma unroll
    for (int j = 0; j < 16; j++) { kv[j] = 0.f; ksl[j] = 0.f; }
    for (int t = 0; t < CHUNK; t++) {
        float ve = vs[t][e];
        f32x4 kr[4];
        #pragma unroll
        for (int s = 0; s < 4; s++) kr[s] = *(const f32x4*)&ks[t][d0 + s * 4];
        #pragma unroll
        for (int j = 0; j < 16; j++) {
            float kval = kr[j >> 2][j & 3];
            kv[j] = fmaf(kval, ve, kv[j]);
            ksl[j] += kval;
        }
    }
    size_t base = (size_t)blk * 1024;
    #pragma unroll
    for (int j = 0; j < 16; j++)
        kvsum[base + (size_t)(d0 + j) * 32 + e] = kv[j];
    if (e == 0) {
        #pragma unroll
        for (int j = 0; j < 16; j++)
            kssum[blk * 32 + d0 + j] = ksl[j];
    }
}

// Phase B: exclusive prefix over chunks, per (b,h).
__global__ __launch_bounds__(256) void attn_prefix(
    const float* __restrict__ kvsum, const float* __restrict__ kssum,
    float* __restrict__ kvpref, float* __restrict__ kspref)
{
    int bh = blockIdx.x;
    int tid = threadIdx.x;
    float run[4] = {0.f, 0.f, 0.f, 0.f};
    for (int c = 0; c < NCH; c++) {
        size_t base = (size_t)(bh * NCH + c) * 1024 + tid * 4;
        #pragma unroll
        for (int q = 0; q < 4; q++) {
            kvpref[base + q] = run[q];
            run[q] += kvsum[base + q];
        }
    }
    if (tid < 32) {
        float r = 0.f;
        for (int c = 0; c < NCH; c++) {
            kspref[(bh * NCH + c) * 32 + tid] = r;
            r += kssum[(bh * NCH + c) * 32 + tid];
        }
    }
}

// Phase C: in-chunk scan, LDS-resident.
__global__ __launch_bounds__(64) void attn_scan(
    const bf16* __restrict__ proj, const float* __restrict__ mask,
    const float* __restrict__ kvpref, const float* __restrict__ kspref,
    bf16* __restrict__ attn_out)
{
    int blk = blockIdx.x;
    int c  = blk & (NCH - 1);
    int bh = blk >> 5;
    int b  = bh >> 4, hh = bh & (HH - 1);
    int lane = threadIdx.x;
    __shared__ float qs[CHUNK][32], ks[CHUNK][32], vs[CHUNK][32];
    __shared__ float ms[CHUNK];
    int row0 = b * TT + c * CHUNK;
    {
        int row = row0 + lane;
        float m = mask[row];
        ms[lane] = m;
        const bf16* qp = proj + (size_t)row * NPROJ + DD + hh * 32;
        const bf16* kp = qp + INNERD;
        const bf16* vp = kp + INNERD;
        #pragma unroll
        for (int s = 0; s < 4; s++) {
            bf16x8 q8 = *(const bf16x8*)(qp + s * 8);
            bf16x8 k8 = *(const bf16x8*)(kp + s * 8);
            bf16x8 v8 = *(const bf16x8*)(vp + s * 8);
            #pragma unroll
            for (int q = 0; q < 8; q++) {
                qs[lane][s * 8 + q] = phi_f((float)q8[q]) * m;
                ks[lane][s * 8 + q] = phi_f((float)k8[q]) * m;
                vs[lane][s * 8 + q] = (float)v8[q] * m;
            }
        }
    }
    int e = lane & 31, d0 = (lane >> 5) * 16;
    float kv[16], ksl[16];
    size_t base = (size_t)blk * 1024;
    #pragma unroll
    for (int j = 0; j < 16; j++) kv[j] = kvpref[base + (size_t)(d0 + j) * 32 + e];
    #pragma unroll
    for (int j = 0; j < 16; j++) ksl[j] = kspref[blk * 32 + d0 + j];
    __syncthreads();
    for (int t = 0; t < CHUNK; t++) {
        float ve = vs[t][e];
        f32x4 kr[4], qr[4];
        #pragma unroll
        for (int s = 0; s < 4; s++) kr[s] = *(const f32x4*)&ks[t][d0 + s * 4];
        #pragma unroll
        for (int s = 0; s < 4; s++) qr[s] = *(const f32x4*)&qs[t][d0 + s * 4];
        float num0 = 0.f, num1 = 0.f, den0 = 0.f, den1 = 0.f;
        #pragma unroll
        for (int j = 0; j < 16; j++) {
            float kval = kr[j >> 2][j & 3], qval = qr[j >> 2][j & 3];
            kv[j]  = fmaf(kval, ve, kv[j]);   // inclusive cumsum
            ksl[j] += kval;
            if (j & 1) { num1 = fmaf(qval, kv[j], num1); den1 = fmaf(qval, ksl[j], den1); }
            else       { num0 = fmaf(qval, kv[j], num0); den0 = fmaf(qval, ksl[j], den0); }
        }
        float num = num0 + num1, den = den0 + den1;
        num += __shfl_xor(num, 32, 64);
        den += __shfl_xor(den, 32, 64);
        if (lane < 32)
            attn_out[(size_t)(row0 + t) * INNERD + hh * 32 + e] =
                (bf16)(num / (den + 1e-6f) * ms[t]);
    }
}

// ---------------------------------------------------------------- launch
extern "C" void kernel_launch(void* const* d_in, const int* in_sizes, int n_in,
                              void* d_out, int out_size, void* d_ws, size_t ws_size,
                              hipStream_t stream)
{
    const float* inputs = (const float*)d_in[0];
    const float* mask   = (const float*)d_in[1];
    const float* ln1_g  = (const float*)d_in[2];
    const float* ln1_b  = (const float*)d_in[3];
    const float* W_in   = (const float*)d_in[4];
    const float* b_in   = (const float*)d_in[5];
    const float* W_c    = (const float*)d_in[6];
    const float* b_c    = (const float*)d_in[7];
    const float* w_t    = (const float*)d_in[8];
    const float* b_t    = (const float*)d_in[9];
    const float* w_p    = (const float*)d_in[10];
    const float* b_p    = (const float*)d_in[11];
    const float* W_mix  = (const float*)d_in[12];
    const float* b_mix  = (const float*)d_in[13];
    const float* ln2_g  = (const float*)d_in[14];
    const float* ln2_b  = (const float*)d_in[15];
    const float* W1     = (const float*)d_in[16];
    const float* b1     = (const float*)d_in[17];
    const float* W2     = (const float*)d_in[18];
    const float* b2     = (const float*)d_in[19];
    float* out = (float*)d_out;

    // workspace layout (bytes). ffn1 aliases [normed|proj|attnb]:
    // 4096*4096 bf16 == 4096*(1024+2560+512) bf16 exactly.
    // attn kv scratch aliases out1 (dead until epi_mix_ln2).
    // Split-K accumulators live in d_out (dead until their GEMM).
    char* p = (char*)d_ws;
    bf16* normed = (bf16*)p;  p += (size_t)MROWS * DD * 2;
    bf16* proj   = (bf16*)p;  p += (size_t)MROWS * NPROJ * 2;
    bf16* attnb  = (bf16*)p;  p += (size_t)MROWS * INNERD * 2;
    bf16* cat    = (bf16*)p;  p += (size_t)MROWS * CATD * 2;
    float* out1  = (float*)p; p += (size_t)MROWS * DD * 4;
    bf16* hbuf   = (bf16*)p;  p += (size_t)MROWS * DD * 2;
    bf16* wt_in  = (bf16*)p;  p += (size_t)NPROJ * DD * 2;
    bf16* wt_c   = (bf16*)p;  p += (size_t)DD * INNERD * 2;
    bf16* wt_mix = (bf16*)p;  p += (size_t)DD * CATD * 2;
    bf16* wt1    = (bf16*)p;  p += (size_t)FFD * DD * 2;
    bf16* wt2    = (bf16*)p;  p += (size_t)DD * FFD * 2;
    bf16* ffn1   = (bf16*)d_ws;                  // alias [normed|proj|attnb]
    float* kvsum = out1;                         // alias out1 region
    float* kvpref= kvsum  + (size_t)BH * NCH * 1024;
    float* kssum = kvpref + (size_t)BH * NCH * 1024;
    float* kspref= kssum  + (size_t)BH * NCH * 32;
    float* S     = (float*)d_out;                // split-K accumulator

    // 0. weight transposes fp32(K,N) -> bf16(N,K)
    transpose_cvt<<<dim3(NPROJ/32, DD/32),   256, 0, stream>>>(W_in,  wt_in,  DD,     NPROJ);
    transpose_cvt<<<dim3(DD/32,    INNERD/32),256, 0, stream>>>(W_c,   wt_c,   INNERD, DD);
    transpose_cvt<<<dim3(DD/32,    CATD/32), 256, 0, stream>>>(W_mix, wt_mix, CATD,   DD);
    transpose_cvt<<<dim3(FFD/32,   DD/32),   256, 0, stream>>>(W1,    wt1,    DD,     FFD);
    transpose_cvt<<<dim3(DD/32,    FFD/32),  256, 0, stream>>>(W2,    wt2,    FFD,    DD);

    // 1. LN1 -> bf16
    layernorm_k<<<MROWS, 256, 0, stream>>>(inputs, ln1_g, ln1_b, normed);
    // 2. proj = normed @ W_in + b_in (bf16 out)
    gemm_mfma<0><<<dim3(NPROJ/128, MROWS/128), 256, 0, stream>>>(
        normed, DD, wt_in, DD, b_in, nullptr, proj, NPROJ, DD);
    // 3. chunked causal linear attention -> attnb (M x 512, bf16)
    attn_sums  <<<BH * NCH, 64, 0, stream>>>(proj, mask, kvsum, kssum);
    attn_prefix<<<BH, 256, 0, stream>>>(kvsum, kssum, kvpref, kspref);
    attn_scan  <<<BH * NCH, 64, 0, stream>>>(proj, mask, kvpref, kspref, attnb);
    // 4. fused depthwise causal convs -> cat[:,D:2D], cat[:,2D:3D]
    dwconv_fused<<<(MROWS/2) * 128 / 256, 256, 0, stream>>>(normed, w_t, b_t, w_p, b_p, cat);
    // 5. cat[:,0:D] = attnb @ W_c + b_c (bf16 out)
    gemm_mfma<0><<<dim3(DD/128, MROWS/128), 256, 0, stream>>>(
        attnb, INNERD, wt_c, INNERD, b_c, nullptr, cat, CATD, INNERD);
    // 6. S = cat @ W_mix (split-K=3, atomic fp32 into d_out)
    hipMemsetAsync(d_out, 0, (size_t)MROWS * DD * 4, stream);
    gemm_mfma<4><<<dim3(DD/128, MROWS/128, 3), 256, 0, stream>>>(
        cat, CATD, wt_mix, CATD, nullptr, S, nullptr, DD, CATD / 3);
    // 7. out1 = (inputs + sigmoid(gate)*(S + b_mix))*mask ; hbuf = LN2(out1)
    epi_mix_ln2<<<MROWS, 256, 0, stream>>>(S, b_mix, proj, inputs, mask,
                                           ln2_g, ln2_b, out1, hbuf);
    // 8. ffn1 = gelu(hbuf @ W1 + b1) (bf16 out; aliases dead normed/proj/attnb)
    gemm_mfma<1><<<dim3(FFD/128, MROWS/128), 256, 0, stream>>>(
        hbuf, DD, wt1, DD, b1, nullptr, ffn1, FFD, DD);
    // 9. S = ffn1 @ W2 (split-K=4, atomic fp32 into d_out)
    hipMemsetAsync(d_out, 0, (size_t)MROWS * DD * 4, stream);
    gemm_mfma<4><<<dim3(DD/128, MROWS/128, 4), 256, 0, stream>>>(
        ffn1, FFD, wt2, FFD, nullptr, S, nullptr, DD, FFD / 4);
    // 10. out = (out1 + S + b2) * mask, in-place on d_out
    epi_w2<<<MROWS * DD / 4 / 256, 256, 0, stream>>>(out, out1, b2, mask);
}

// Round 5
// 508.510 us; speedup vs baseline: 4.2944x; 1.0623x over previous
//
#include <hip/hip_runtime.h>
#include <math.h>

#define BB 2
#define TT 2048
#define DD 1024
#define HH 16
#define INNERD 512
#define FFD 4096
#define NPROJ 2560     // D + 3*INNER
#define CATD 3072      // 3*D
#define MROWS (BB*TT)  // 4096
#define CHUNK 64
#define NCH (TT/CHUNK) // 32
#define BH 32          // B*H

typedef __bf16 bf16;
typedef __attribute__((ext_vector_type(8))) __bf16 bf16x8;
typedef __attribute__((ext_vector_type(4))) __bf16 bf16x4;
typedef __attribute__((ext_vector_type(4))) float f32x4;

// ---------------------------------------------------------------- layernorm -> bf16 (vectorized)
__global__ __launch_bounds__(256) void layernorm_k(
    const float* __restrict__ x, const float* __restrict__ g,
    const float* __restrict__ bta, bf16* __restrict__ y)
{
    int row = blockIdx.x, tid = threadIdx.x;
    f32x4 xv = ((const f32x4*)(x + (size_t)row * DD))[tid];
    float s = xv[0] + xv[1] + xv[2] + xv[3];
    float s2 = xv[0]*xv[0] + xv[1]*xv[1] + xv[2]*xv[2] + xv[3]*xv[3];
    #pragma unroll
    for (int off = 32; off > 0; off >>= 1) {
        s  += __shfl_xor(s,  off, 64);
        s2 += __shfl_xor(s2, off, 64);
    }
    __shared__ float rs[4], rs2[4];
    int wid = tid >> 6;
    if ((tid & 63) == 0) { rs[wid] = s; rs2[wid] = s2; }
    __syncthreads();
    s  = rs[0] + rs[1] + rs[2] + rs[3];
    s2 = rs2[0] + rs2[1] + rs2[2] + rs2[3];
    float mean = s * (1.0f / DD);
    float var  = s2 * (1.0f / DD) - mean * mean;
    float rstd = rsqrtf(var + 1e-5f);
    f32x4 gv = ((const f32x4*)g)[tid];
    f32x4 bv = ((const f32x4*)bta)[tid];
    bf16x4 o;
    #pragma unroll
    for (int q = 0; q < 4; q++)
        o[q] = (bf16)((xv[q] - mean) * rstd * gv[q] + bv[q]);
    ((bf16x4*)(y + (size_t)row * DD))[tid] = o;
}

// ---------------------------------------------------------------- weight transpose fp32(K,N) -> bf16(N,K)
__global__ __launch_bounds__(256) void transpose_cvt(
    const float* __restrict__ W, bf16* __restrict__ Wt, int Kd, int Nd)
{
    __shared__ float t[32][33];
    int nb = blockIdx.x * 32, kb = blockIdx.y * 32;
    int tx = threadIdx.x & 31, ty = threadIdx.x >> 5;   // 32 x 8
    #pragma unroll
    for (int r = 0; r < 32; r += 8)
        t[ty + r][tx] = W[(size_t)(kb + ty + r) * Nd + nb + tx];
    __syncthreads();
    #pragma unroll
    for (int r = 0; r < 32; r += 8)
        Wt[(size_t)(nb + ty + r) * Kd + kb + tx] = (bf16)t[tx][ty + r];
}

// ---------------------------------------------------------------- MFMA GEMM, BK=64, 4 blocks/CU
// C = epilogue(A[M,koff:koff+K] @ Bt[N,koff:koff+K]^T [+ bias])
// EPI 0: +bias -> bf16   EPI 1: fast-gelu(+bias) -> bf16
// EPI 4: fp32 atomic accumulate (no bias); koff = blockIdx.z * K
template<int EPI>
__global__ __launch_bounds__(256, 4) void gemm_mfma(
    const bf16* __restrict__ A,  int lda,
    const bf16* __restrict__ Bt, int ldb,
    const float* __restrict__ bias,
    float* __restrict__ Cf, bf16* __restrict__ Cb, int ldc,
    int K)
{
    __shared__ bf16 As[128 * 64];   // chunk-contiguous: 16 chunks of 16rows x 32k
    __shared__ bf16 Bs[128 * 64];
    const int tid  = threadIdx.x;
    const int wave = tid >> 6, lane = tid & 63;
    const int m0 = blockIdx.y * 128, n0 = blockIdx.x * 128;
    const int koff = blockIdx.z * K;
    A  += koff;
    Bt += koff;
    const int wr = wave >> 1, wc = wave & 1;
    const int lrow = lane >> 2;          // staging row within 16-row chunk
    const int lcol = (lane & 3) * 8;     // staging k offset within 32-k half
    const int fm = lane & 15;            // fragment m/n within 16-tile
    const int fk = (lane >> 4) * 8;      // fragment k offset

    f32x4 acc[4][4];
    #pragma unroll
    for (int i = 0; i < 4; i++)
        #pragma unroll
        for (int j = 0; j < 4; j++)
            acc[i][j] = (f32x4){0.f, 0.f, 0.f, 0.f};

    for (int k0 = 0; k0 < K; k0 += 64) {
        #pragma unroll
        for (int r = 0; r < 4; r++) {
            int c  = r * 4 + wave;            // chunk 0..15
            int rc = c >> 1, kh = c & 1;      // row-chunk, k-half
            const bf16* ga = A  + (size_t)(m0 + rc * 16 + lrow) * lda + k0 + kh * 32 + lcol;
            const bf16* gb = Bt + (size_t)(n0 + rc * 16 + lrow) * ldb + k0 + kh * 32 + lcol;
            __builtin_amdgcn_global_load_lds(
                (const __attribute__((address_space(1))) void*)ga,
                (__attribute__((address_space(3))) void*)(As + c * 512), 16, 0, 0);
            __builtin_amdgcn_global_load_lds(
                (const __attribute__((address_space(1))) void*)gb,
                (__attribute__((address_space(3))) void*)(Bs + c * 512), 16, 0, 0);
        }
        __syncthreads();
        #pragma unroll
        for (int ks = 0; ks < 2; ks++) {
            bf16x8 af[4], bfv[4];
            #pragma unroll
            for (int i = 0; i < 4; i++)
                af[i] = *(const bf16x8*)(As + (wr * 4 + i) * 1024 + ks * 512 + fm * 32 + fk);
            #pragma unroll
            for (int j = 0; j < 4; j++)
                bfv[j] = *(const bf16x8*)(Bs + (wc * 4 + j) * 1024 + ks * 512 + fm * 32 + fk);
            #pragma unroll
            for (int i = 0; i < 4; i++)
                #pragma unroll
                for (int j = 0; j < 4; j++)
                    acc[i][j] = __builtin_amdgcn_mfma_f32_16x16x32_bf16(
                        af[i], bfv[j], acc[i][j], 0, 0, 0);
        }
        __syncthreads();
    }

    #pragma unroll
    for (int i = 0; i < 4; i++) {
        int mbase = m0 + wr * 64 + i * 16 + (lane >> 4) * 4;
        #pragma unroll
        for (int j = 0; j < 4; j++) {
            int col = n0 + wc * 64 + j * 16 + (lane & 15);
            float bv = 0.f;
            if constexpr (EPI != 4) bv = bias[col];
            #pragma unroll
            for (int r = 0; r < 4; r++) {
                int row = mbase + r;
                float v = acc[i][j][r] + bv;
                if constexpr (EPI == 0) {
                    Cb[(size_t)row * ldc + col] = (bf16)v;
                } else if constexpr (EPI == 1) {
                    // fast gelu: x * sigmoid(1.5957691x + 0.07135502x^3)
                    float z = v * (1.5957691f + 0.07135502f * v * v);
                    v = v / (1.0f + __expf(-z));
                    Cb[(size_t)row * ldc + col] = (bf16)v;
                } else {
                    unsafeAtomicAdd(&Cf[(size_t)row * ldc + col], v);
                }
            }
        }
    }
}

// ---------------------------------------------------------------- epilogue: cat[:,0:D] = bf16(Sc + b_c)
__global__ __launch_bounds__(256) void epi_wc(
    const float* __restrict__ Sc, const float* __restrict__ bias,
    bf16* __restrict__ cat)
{
    int id = blockIdx.x * 256 + threadIdx.x;    // over MROWS*DD/4
    int row = id >> 8, cg = id & 255;
    f32x4 s = ((const f32x4*)Sc)[id];
    f32x4 b = ((const f32x4*)bias)[cg];
    bf16x4 o;
    #pragma unroll
    for (int q = 0; q < 4; q++) o[q] = (bf16)(s[q] + b[q]);
    *(bf16x4*)(cat + (size_t)row * CATD + cg * 4) = o;
}

// ---------------------------------------------------------------- fused epilogue: W_mix gate + residual + mask, then LN2
__global__ __launch_bounds__(256) void epi_mix_ln2(
    const float* __restrict__ S, const float* __restrict__ bias,
    const bf16* __restrict__ proj, const float* __restrict__ res,
    const float* __restrict__ mask,
    const float* __restrict__ g2, const float* __restrict__ b2v,
    float* __restrict__ out1, bf16* __restrict__ hbuf)
{
    int row = blockIdx.x, tid = threadIdx.x;
    float m = mask[row];
    f32x4 sv = ((const f32x4*)(S + (size_t)row * DD))[tid];
    f32x4 bv = ((const f32x4*)bias)[tid];
    bf16x4 g4 = *(const bf16x4*)(proj + (size_t)row * NPROJ + tid * 4);
    f32x4 rv = ((const f32x4*)(res + (size_t)row * DD))[tid];
    f32x4 v;
    #pragma unroll
    for (int q = 0; q < 4; q++) {
        float sg = 1.0f / (1.0f + __expf(-(float)g4[q]));
        v[q] = (rv[q] + sg * (sv[q] + bv[q])) * m;
    }
    ((f32x4*)(out1 + (size_t)row * DD))[tid] = v;
    // LN2
    float s = v[0] + v[1] + v[2] + v[3];
    float s2 = v[0]*v[0] + v[1]*v[1] + v[2]*v[2] + v[3]*v[3];
    #pragma unroll
    for (int off = 32; off > 0; off >>= 1) {
        s  += __shfl_xor(s,  off, 64);
        s2 += __shfl_xor(s2, off, 64);
    }
    __shared__ float rs[4], rs2[4];
    int wid = tid >> 6;
    if ((tid & 63) == 0) { rs[wid] = s; rs2[wid] = s2; }
    __syncthreads();
    s  = rs[0] + rs[1] + rs[2] + rs[3];
    s2 = rs2[0] + rs2[1] + rs2[2] + rs2[3];
    float mean = s * (1.0f / DD);
    float var  = s2 * (1.0f / DD) - mean * mean;
    float rstd = rsqrtf(var + 1e-5f);
    f32x4 gg = ((const f32x4*)g2)[tid];
    f32x4 bb = ((const f32x4*)b2v)[tid];
    bf16x4 h;
    #pragma unroll
    for (int q = 0; q < 4; q++)
        h[q] = (bf16)((v[q] - mean) * rstd * gg[q] + bb[q]);
    ((bf16x4*)(hbuf + (size_t)row * DD))[tid] = h;
}

// ---------------------------------------------------------------- final epilogue: out = (out1 + S + b2) * mask, in-place on d_out
__global__ __launch_bounds__(256) void epi_w2(
    float* __restrict__ d_out, const float* __restrict__ out1,
    const float* __restrict__ bias, const float* __restrict__ mask)
{
    int id = blockIdx.x * 256 + threadIdx.x;    // over MROWS*DD/4
    int row = id >> 8;                          // 256 f32x4 per row
    float m = mask[row];
    f32x4 a = ((const f32x4*)d_out)[id];
    f32x4 r = ((const f32x4*)out1)[id];
    f32x4 b = ((const f32x4*)bias)[id & 255];
    f32x4 o;
    #pragma unroll
    for (int q = 0; q < 4; q++) o[q] = (r[q] + a[q] + b[q]) * m;
    ((f32x4*)d_out)[id] = o;
}

// ---------------------------------------------------------------- fused dwconv (both kernels, 2 rows/thread, vectorized)
__global__ __launch_bounds__(256) void dwconv_fused(
    const bf16* __restrict__ x,
    const float* __restrict__ w_t, const float* __restrict__ b_t,
    const float* __restrict__ w_p, const float* __restrict__ b_p,
    bf16* __restrict__ cat)
{
    int id = blockIdx.x * 256 + threadIdx.x;    // over (MROWS/2)*128
    int cg = id & 127, rp = id >> 7;
    int c0 = cg * 8;
    int row0 = rp * 2;
    int t0 = row0 & (TT - 1);
    bf16x8 xw[16];
    #pragma unroll
    for (int j = 0; j < 16; j++) {
        int t = t0 - 14 + j;
        if (t >= 0)
            xw[j] = *(const bf16x8*)(x + (size_t)(row0 - 14 + j) * DD + c0);
        else
            #pragma unroll
            for (int q = 0; q < 8; q++) xw[j][q] = (bf16)0.f;
    }
    float y15[2][8], y3[2][8];
    #pragma unroll
    for (int q = 0; q < 8; q++) {
        float bp = b_p[c0 + q], bt = b_t[c0 + q];
        y15[0][q] = bp; y15[1][q] = bp;
        y3[0][q] = bt;  y3[1][q] = bt;
    }
    #pragma unroll
    for (int i = 0; i < 15; i++) {
        float wp[8];
        #pragma unroll
        for (int q = 0; q < 8; q++) wp[q] = w_p[(c0 + q) * 15 + i];
        #pragma unroll
        for (int rr = 0; rr < 2; rr++)
            #pragma unroll
            for (int q = 0; q < 8; q++)
                y15[rr][q] = fmaf(wp[q], (float)xw[rr + i][q], y15[rr][q]);
    }
    #pragma unroll
    for (int i = 0; i < 3; i++) {
        float wt[8];
        #pragma unroll
        for (int q = 0; q < 8; q++) wt[q] = w_t[(c0 + q) * 3 + i];
        #pragma unroll
        for (int rr = 0; rr < 2; rr++)
            #pragma unroll
            for (int q = 0; q < 8; q++)
                y3[rr][q] = fmaf(wt[q], (float)xw[rr + 12 + i][q], y3[rr][q]);
    }
    #pragma unroll
    for (int rr = 0; rr < 2; rr++) {
        bf16x8 o3, o15;
        #pragma unroll
        for (int q = 0; q < 8; q++) { o3[q] = (bf16)y3[rr][q]; o15[q] = (bf16)y15[rr][q]; }
        *(bf16x8*)(cat + (size_t)(row0 + rr) * CATD + DD + c0)     = o3;
        *(bf16x8*)(cat + (size_t)(row0 + rr) * CATD + 2 * DD + c0) = o15;
    }
}

// ---------------------------------------------------------------- attention
__device__ __forceinline__ float phi_f(float x) {
    return x > 0.f ? x + 1.f : __expf(x);   // elu(x)+1
}

// Phase A: per-(b,h,chunk) local sums, LDS-resident. One wave/block, lane==t.
__global__ __launch_bounds__(64) void attn_sums(
    const bf16* __restrict__ proj, const float* __restrict__ mask,
    float* __restrict__ kvsum, float* __restrict__ kssum)
{
    int blk = blockIdx.x;              // bh*NCH + c
    int c  = blk & (NCH - 1);
    int bh = blk >> 5;
    int b  = bh >> 4, hh = bh & (HH - 1);
    int lane = threadIdx.x;
    __shared__ float ks[CHUNK][32], vs[CHUNK][32];
    int row0 = b * TT + c * CHUNK;
    {
        int row = row0 + lane;
        float m = mask[row];
        const bf16* kp = proj + (size_t)row * NPROJ + DD + INNERD + hh * 32;
        const bf16* vp = kp + INNERD;
        #pragma unroll
        for (int s = 0; s < 4; s++) {
            bf16x8 k8 = *(const bf16x8*)(kp + s * 8);
            bf16x8 v8 = *(const bf16x8*)(vp + s * 8);
            #pragma unroll
            for (int q = 0; q < 8; q++) {
                ks[lane][s * 8 + q] = phi_f((float)k8[q]) * m;
                vs[lane][s * 8 + q] = (float)v8[q] * m;
            }
        }
    }
    __syncthreads();
    int e = lane & 31, d0 = (lane >> 5) * 16;
    float kv[16], ksl[16];
    #pragma unroll
    for (int j = 0; j < 16; j++) { kv[j] = 0.f; ksl[j] = 0.f; }
    for (int t = 0; t < CHUNK; t++) {
        float ve = vs[t][e];
        f32x4 kr[4];
        #pragma unroll
        for (int s = 0; s < 4; s++) kr[s] = *(const f32x4*)&ks[t][d0 + s * 4];
        #pragma unroll
        for (int j = 0; j < 16; j++) {
            float kval = kr[j >> 2][j & 3];
            kv[j] = fmaf(kval, ve, kv[j]);
            ksl[j] += kval;
        }
    }
    size_t base = (size_t)blk * 1024;
    #pragma unroll
    for (int j = 0; j < 16; j++)
        kvsum[base + (size_t)(d0 + j) * 32 + e] = kv[j];
    if (e == 0) {
        #pragma unroll
        for (int j = 0; j < 16; j++)
            kssum[blk * 32 + d0 + j] = ksl[j];
    }
}

// Phase B: exclusive prefix over chunks, per (b,h).
__global__ __launch_bounds__(256) void attn_prefix(
    const float* __restrict__ kvsum, const float* __restrict__ kssum,
    float* __restrict__ kvpref, float* __restrict__ kspref)
{
    int bh = blockIdx.x;
    int tid = threadIdx.x;
    float run[4] = {0.f, 0.f, 0.f, 0.f};
    for (int c = 0; c < NCH; c++) {
        size_t base = (size_t)(bh * NCH + c) * 1024 + tid * 4;
        #pragma unroll
        for (int q = 0; q < 4; q++) {
            kvpref[base + q] = run[q];
            run[q] += kvsum[base + q];
        }
    }
    if (tid < 32) {
        float r = 0.f;
        for (int c = 0; c < NCH; c++) {
            kspref[(bh * NCH + c) * 32 + tid] = r;
            r += kssum[(bh * NCH + c) * 32 + tid];
        }
    }
}

// Phase C: in-chunk scan, LDS-resident.
__global__ __launch_bounds__(64) void attn_scan(
    const bf16* __restrict__ proj, const float* __restrict__ mask,
    const float* __restrict__ kvpref, const float* __restrict__ kspref,
    bf16* __restrict__ attn_out)
{
    int blk = blockIdx.x;
    int c  = blk & (NCH - 1);
    int bh = blk >> 5;
    int b  = bh >> 4, hh = bh & (HH - 1);
    int lane = threadIdx.x;
    __shared__ float qs[CHUNK][32], ks[CHUNK][32], vs[CHUNK][32];
    __shared__ float ms[CHUNK];
    int row0 = b * TT + c * CHUNK;
    {
        int row = row0 + lane;
        float m = mask[row];
        ms[lane] = m;
        const bf16* qp = proj + (size_t)row * NPROJ + DD + hh * 32;
        const bf16* kp = qp + INNERD;
        const bf16* vp = kp + INNERD;
        #pragma unroll
        for (int s = 0; s < 4; s++) {
            bf16x8 q8 = *(const bf16x8*)(qp + s * 8);
            bf16x8 k8 = *(const bf16x8*)(kp + s * 8);
            bf16x8 v8 = *(const bf16x8*)(vp + s * 8);
            #pragma unroll
            for (int q = 0; q < 8; q++) {
                qs[lane][s * 8 + q] = phi_f((float)q8[q]) * m;
                ks[lane][s * 8 + q] = phi_f((float)k8[q]) * m;
                vs[lane][s * 8 + q] = (float)v8[q] * m;
            }
        }
    }
    int e = lane & 31, d0 = (lane >> 5) * 16;
    float kv[16], ksl[16];
    size_t base = (size_t)blk * 1024;
    #pragma unroll
    for (int j = 0; j < 16; j++) kv[j] = kvpref[base + (size_t)(d0 + j) * 32 + e];
    #pragma unroll
    for (int j = 0; j < 16; j++) ksl[j] = kspref[blk * 32 + d0 + j];
    __syncthreads();
    for (int t = 0; t < CHUNK; t++) {
        float ve = vs[t][e];
        f32x4 kr[4], qr[4];
        #pragma unroll
        for (int s = 0; s < 4; s++) kr[s] = *(const f32x4*)&ks[t][d0 + s * 4];
        #pragma unroll
        for (int s = 0; s < 4; s++) qr[s] = *(const f32x4*)&qs[t][d0 + s * 4];
        float num0 = 0.f, num1 = 0.f, den0 = 0.f, den1 = 0.f;
        #pragma unroll
        for (int j = 0; j < 16; j++) {
            float kval = kr[j >> 2][j & 3], qval = qr[j >> 2][j & 3];
            kv[j]  = fmaf(kval, ve, kv[j]);   // inclusive cumsum
            ksl[j] += kval;
            if (j & 1) { num1 = fmaf(qval, kv[j], num1); den1 = fmaf(qval, ksl[j], den1); }
            else       { num0 = fmaf(qval, kv[j], num0); den0 = fmaf(qval, ksl[j], den0); }
        }
        float num = num0 + num1, den = den0 + den1;
        num += __shfl_xor(num, 32, 64);
        den += __shfl_xor(den, 32, 64);
        if (lane < 32)
            attn_out[(size_t)(row0 + t) * INNERD + hh * 32 + e] =
                (bf16)(num / (den + 1e-6f) * ms[t]);
    }
}

// ---------------------------------------------------------------- launch
extern "C" void kernel_launch(void* const* d_in, const int* in_sizes, int n_in,
                              void* d_out, int out_size, void* d_ws, size_t ws_size,
                              hipStream_t stream)
{
    const float* inputs = (const float*)d_in[0];
    const float* mask   = (const float*)d_in[1];
    const float* ln1_g  = (const float*)d_in[2];
    const float* ln1_b  = (const float*)d_in[3];
    const float* W_in   = (const float*)d_in[4];
    const float* b_in   = (const float*)d_in[5];
    const float* W_c    = (const float*)d_in[6];
    const float* b_c    = (const float*)d_in[7];
    const float* w_t    = (const float*)d_in[8];
    const float* b_t    = (const float*)d_in[9];
    const float* w_p    = (const float*)d_in[10];
    const float* b_p    = (const float*)d_in[11];
    const float* W_mix  = (const float*)d_in[12];
    const float* b_mix  = (const float*)d_in[13];
    const float* ln2_g  = (const float*)d_in[14];
    const float* ln2_b  = (const float*)d_in[15];
    const float* W1     = (const float*)d_in[16];
    const float* b1     = (const float*)d_in[17];
    const float* W2     = (const float*)d_in[18];
    const float* b2     = (const float*)d_in[19];
    float* out = (float*)d_out;

    // workspace layout (bytes). ffn1 aliases [normed|proj|attnb] (dead by W1).
    // attn kv scratch AND W_c's split-K accumulator alias out1 (dead until
    // epi_mix_ln2). W_mix/W2 split-K accumulators live in d_out.
    char* p = (char*)d_ws;
    bf16* normed = (bf16*)p;  p += (size_t)MROWS * DD * 2;
    bf16* proj   = (bf16*)p;  p += (size_t)MROWS * NPROJ * 2;
    bf16* attnb  = (bf16*)p;  p += (size_t)MROWS * INNERD * 2;
    bf16* cat    = (bf16*)p;  p += (size_t)MROWS * CATD * 2;
    float* out1  = (float*)p; p += (size_t)MROWS * DD * 4;
    bf16* hbuf   = (bf16*)p;  p += (size_t)MROWS * DD * 2;
    bf16* wt_in  = (bf16*)p;  p += (size_t)NPROJ * DD * 2;
    bf16* wt_c   = (bf16*)p;  p += (size_t)DD * INNERD * 2;
    bf16* wt_mix = (bf16*)p;  p += (size_t)DD * CATD * 2;
    bf16* wt1    = (bf16*)p;  p += (size_t)FFD * DD * 2;
    bf16* wt2    = (bf16*)p;  p += (size_t)DD * FFD * 2;
    bf16* ffn1   = (bf16*)d_ws;                  // alias [normed|proj|attnb]
    float* kvsum = out1;                         // alias out1 region
    float* kvpref= kvsum  + (size_t)BH * NCH * 1024;
    float* kssum = kvpref + (size_t)BH * NCH * 1024;
    float* kspref= kssum  + (size_t)BH * NCH * 32;
    float* Sc    = out1;                         // W_c accumulator (after attn)
    float* S     = (float*)d_out;                // W_mix / W2 accumulator

    // 0. weight transposes fp32(K,N) -> bf16(N,K)
    transpose_cvt<<<dim3(NPROJ/32, DD/32),   256, 0, stream>>>(W_in,  wt_in,  DD,     NPROJ);
    transpose_cvt<<<dim3(DD/32,    INNERD/32),256, 0, stream>>>(W_c,   wt_c,   INNERD, DD);
    transpose_cvt<<<dim3(DD/32,    CATD/32), 256, 0, stream>>>(W_mix, wt_mix, CATD,   DD);
    transpose_cvt<<<dim3(FFD/32,   DD/32),   256, 0, stream>>>(W1,    wt1,    DD,     FFD);
    transpose_cvt<<<dim3(DD/32,    FFD/32),  256, 0, stream>>>(W2,    wt2,    FFD,    DD);

    // 1. LN1 -> bf16
    layernorm_k<<<MROWS, 256, 0, stream>>>(inputs, ln1_g, ln1_b, normed);
    // 2. proj = normed @ W_in + b_in (bf16 out)
    gemm_mfma<0><<<dim3(NPROJ/128, MROWS/128), 256, 0, stream>>>(
        normed, DD, wt_in, DD, b_in, nullptr, proj, NPROJ, DD);
    // 3. chunked causal linear attention -> attnb (M x 512, bf16)
    attn_sums  <<<BH * NCH, 64, 0, stream>>>(proj, mask, kvsum, kssum);
    attn_prefix<<<BH, 256, 0, stream>>>(kvsum, kssum, kvpref, kspref);
    attn_scan  <<<BH * NCH, 64, 0, stream>>>(proj, mask, kvpref, kspref, attnb);
    // 4. fused depthwise causal convs -> cat[:,D:2D], cat[:,2D:3D]
    dwconv_fused<<<(MROWS/2) * 128 / 256, 256, 0, stream>>>(normed, w_t, b_t, w_p, b_p, cat);
    // 5. Sc = attnb @ W_c (split-K=2, atomic fp32), then cat[:,0:D] = bf16(Sc + b_c)
    hipMemsetAsync(Sc, 0, (size_t)MROWS * DD * 4, stream);
    gemm_mfma<4><<<dim3(DD/128, MROWS/128, 2), 256, 0, stream>>>(
        attnb, INNERD, wt_c, INNERD, nullptr, Sc, nullptr, DD, INNERD / 2);
    epi_wc<<<MROWS * DD / 4 / 256, 256, 0, stream>>>(Sc, b_c, cat);
    // 6. S = cat @ W_mix (split-K=3, atomic fp32 into d_out)
    hipMemsetAsync(d_out, 0, (size_t)MROWS * DD * 4, stream);
    gemm_mfma<4><<<dim3(DD/128, MROWS/128, 3), 256, 0, stream>>>(
        cat, CATD, wt_mix, CATD, nullptr, S, nullptr, DD, CATD / 3);
    // 7. out1 = (inputs + sigmoid(gate)*(S + b_mix))*mask ; hbuf = LN2(out1)
    epi_mix_ln2<<<MROWS, 256, 0, stream>>>(S, b_mix, proj, inputs, mask,
                                           ln2_g, ln2_b, out1, hbuf);
    // 8. ffn1 = gelu(hbuf @ W1 + b1) (bf16 out; aliases dead normed/proj/attnb)
    gemm_mfma<1><<<dim3(FFD/128, MROWS/128), 256, 0, stream>>>(
        hbuf, DD, wt1, DD, b1, nullptr, ffn1, FFD, DD);
    // 9. S = ffn1 @ W2 (split-K=4, atomic fp32 into d_out)
    hipMemsetAsync(d_out, 0, (size_t)MROWS * DD * 4, stream);
    gemm_mfma<4><<<dim3(DD/128, MROWS/128, 4), 256, 0, stream>>>(
        ffn1, FFD, wt2, FFD, nullptr, S, nullptr, DD, FFD / 4);
    // 10. out = (out1 + S + b2) * mask, in-place on d_out
    epi_w2<<<MROWS * DD / 4 / 256, 256, 0, stream>>>(out, out1, b2, mask);
}

// Round 6
// 426.209 us; speedup vs baseline: 5.1237x; 1.1931x over previous
//
#include <hip/hip_runtime.h>
#include <math.h>

#define BB 2
#define TT 2048
#define DD 1024
#define HH 16
#define INNERD 512
#define FFD 4096
#define NPROJ 2560     // D + 3*INNER
#define CATD 3072      // 3*D
#define MROWS (BB*TT)  // 4096
#define CHUNK 64
#define NCH (TT/CHUNK) // 32
#define BH 32          // B*H

typedef __bf16 bf16;
typedef __attribute__((ext_vector_type(8))) __bf16 bf16x8;
typedef __attribute__((ext_vector_type(4))) __bf16 bf16x4;
typedef __attribute__((ext_vector_type(4))) float f32x4;

struct Part4 { void* p0; void* p1; void* p2; void* p3; };

// ---------------------------------------------------------------- layernorm -> bf16 (vectorized)
__global__ __launch_bounds__(256) void layernorm_k(
    const float* __restrict__ x, const float* __restrict__ g,
    const float* __restrict__ bta, bf16* __restrict__ y)
{
    int row = blockIdx.x, tid = threadIdx.x;
    f32x4 xv = ((const f32x4*)(x + (size_t)row * DD))[tid];
    float s = xv[0] + xv[1] + xv[2] + xv[3];
    float s2 = xv[0]*xv[0] + xv[1]*xv[1] + xv[2]*xv[2] + xv[3]*xv[3];
    #pragma unroll
    for (int off = 32; off > 0; off >>= 1) {
        s  += __shfl_xor(s,  off, 64);
        s2 += __shfl_xor(s2, off, 64);
    }
    __shared__ float rs[4], rs2[4];
    int wid = tid >> 6;
    if ((tid & 63) == 0) { rs[wid] = s; rs2[wid] = s2; }
    __syncthreads();
    s  = rs[0] + rs[1] + rs[2] + rs[3];
    s2 = rs2[0] + rs2[1] + rs2[2] + rs2[3];
    float mean = s * (1.0f / DD);
    float var  = s2 * (1.0f / DD) - mean * mean;
    float rstd = rsqrtf(var + 1e-5f);
    f32x4 gv = ((const f32x4*)g)[tid];
    f32x4 bv = ((const f32x4*)bta)[tid];
    bf16x4 o;
    #pragma unroll
    for (int q = 0; q < 4; q++)
        o[q] = (bf16)((xv[q] - mean) * rstd * gv[q] + bv[q]);
    ((bf16x4*)(y + (size_t)row * DD))[tid] = o;
}

// ---------------------------------------------------------------- weight transpose fp32(K,N) -> bf16(N,K)
__global__ __launch_bounds__(256) void transpose_cvt(
    const float* __restrict__ W, bf16* __restrict__ Wt, int Kd, int Nd)
{
    __shared__ float t[32][33];
    int nb = blockIdx.x * 32, kb = blockIdx.y * 32;
    int tx = threadIdx.x & 31, ty = threadIdx.x >> 5;   // 32 x 8
    #pragma unroll
    for (int r = 0; r < 32; r += 8)
        t[ty + r][tx] = W[(size_t)(kb + ty + r) * Nd + nb + tx];
    __syncthreads();
    #pragma unroll
    for (int r = 0; r < 32; r += 8)
        Wt[(size_t)(nb + ty + r) * Kd + kb + tx] = (bf16)t[tx][ty + r];
}

// ---------------------------------------------------------------- MFMA GEMM, BK=64, 4 blocks/CU
// C = epilogue(A[M,koff:koff+K] @ Bt[N,koff:koff+K]^T [+ bias])
// EPI 0: +bias -> bf16 Cb      EPI 1: fast-gelu(+bias) -> bf16 Cb
// EPI 4: bf16 partial -> part.p[z] (ldc=DD)
// EPI 5: fp32 partial -> part.p[z] (ldc=DD)
template<int EPI>
__global__ __launch_bounds__(256, 4) void gemm_mfma(
    const bf16* __restrict__ A,  int lda,
    const bf16* __restrict__ Bt, int ldb,
    const float* __restrict__ bias,
    bf16* __restrict__ Cb, int ldc,
    int K, Part4 part)
{
    __shared__ bf16 As[128 * 64];   // chunk-contiguous: 16 chunks of 16rows x 32k
    __shared__ bf16 Bs[128 * 64];
    const int tid  = threadIdx.x;
    const int wave = tid >> 6, lane = tid & 63;
    const int m0 = blockIdx.y * 128, n0 = blockIdx.x * 128;
    const int koff = blockIdx.z * K;
    A  += koff;
    Bt += koff;
    const int wr = wave >> 1, wc = wave & 1;
    const int lrow = lane >> 2;          // staging row within 16-row chunk
    const int lcol = (lane & 3) * 8;     // staging k offset within 32-k half
    const int fm = lane & 15;            // fragment m/n within 16-tile
    const int fk = (lane >> 4) * 8;      // fragment k offset

    f32x4 acc[4][4];
    #pragma unroll
    for (int i = 0; i < 4; i++)
        #pragma unroll
        for (int j = 0; j < 4; j++)
            acc[i][j] = (f32x4){0.f, 0.f, 0.f, 0.f};

    for (int k0 = 0; k0 < K; k0 += 64) {
        #pragma unroll
        for (int r = 0; r < 4; r++) {
            int c  = r * 4 + wave;            // chunk 0..15
            int rc = c >> 1, kh = c & 1;      // row-chunk, k-half
            const bf16* ga = A  + (size_t)(m0 + rc * 16 + lrow) * lda + k0 + kh * 32 + lcol;
            const bf16* gb = Bt + (size_t)(n0 + rc * 16 + lrow) * ldb + k0 + kh * 32 + lcol;
            __builtin_amdgcn_global_load_lds(
                (const __attribute__((address_space(1))) void*)ga,
                (__attribute__((address_space(3))) void*)(As + c * 512), 16, 0, 0);
            __builtin_amdgcn_global_load_lds(
                (const __attribute__((address_space(1))) void*)gb,
                (__attribute__((address_space(3))) void*)(Bs + c * 512), 16, 0, 0);
        }
        __syncthreads();
        #pragma unroll
        for (int ks = 0; ks < 2; ks++) {
            bf16x8 af[4], bfv[4];
            #pragma unroll
            for (int i = 0; i < 4; i++)
                af[i] = *(const bf16x8*)(As + (wr * 4 + i) * 1024 + ks * 512 + fm * 32 + fk);
            #pragma unroll
            for (int j = 0; j < 4; j++)
                bfv[j] = *(const bf16x8*)(Bs + (wc * 4 + j) * 1024 + ks * 512 + fm * 32 + fk);
            #pragma unroll
            for (int i = 0; i < 4; i++)
                #pragma unroll
                for (int j = 0; j < 4; j++)
                    acc[i][j] = __builtin_amdgcn_mfma_f32_16x16x32_bf16(
                        af[i], bfv[j], acc[i][j], 0, 0, 0);
        }
        __syncthreads();
    }

    void* psel = nullptr;
    if constexpr (EPI == 4 || EPI == 5) {
        int z = blockIdx.z;
        psel = (z == 0) ? part.p0 : (z == 1) ? part.p1 : (z == 2) ? part.p2 : part.p3;
    }

    #pragma unroll
    for (int i = 0; i < 4; i++) {
        int mbase = m0 + wr * 64 + i * 16 + (lane >> 4) * 4;
        #pragma unroll
        for (int j = 0; j < 4; j++) {
            int col = n0 + wc * 64 + j * 16 + (lane & 15);
            float bv = 0.f;
            if constexpr (EPI == 0 || EPI == 1) bv = bias[col];
            #pragma unroll
            for (int r = 0; r < 4; r++) {
                int row = mbase + r;
                float v = acc[i][j][r] + bv;
                if constexpr (EPI == 0) {
                    Cb[(size_t)row * ldc + col] = (bf16)v;
                } else if constexpr (EPI == 1) {
                    // fast gelu: x * sigmoid(1.5957691x + 0.07135502x^3)
                    float z2 = v * (1.5957691f + 0.07135502f * v * v);
                    v = v / (1.0f + __expf(-z2));
                    Cb[(size_t)row * ldc + col] = (bf16)v;
                } else if constexpr (EPI == 4) {
                    ((bf16*)psel)[(size_t)row * DD + col] = (bf16)v;
                } else {
                    ((float*)psel)[(size_t)row * DD + col] = v;
                }
            }
        }
    }
}

// ---------------------------------------------------------------- epilogue: cat[:,0:D] = bf16(P0 + P1 + b_c)
__global__ __launch_bounds__(256) void epi_wc(
    const float* __restrict__ P0, const float* __restrict__ P1,
    const float* __restrict__ bias, bf16* __restrict__ cat)
{
    int id = blockIdx.x * 256 + threadIdx.x;    // over MROWS*DD/4
    int row = id >> 8, cg = id & 255;
    f32x4 s0 = ((const f32x4*)P0)[id];
    f32x4 s1 = ((const f32x4*)P1)[id];
    f32x4 b  = ((const f32x4*)bias)[cg];
    bf16x4 o;
    #pragma unroll
    for (int q = 0; q < 4; q++) o[q] = (bf16)(s0[q] + s1[q] + b[q]);
    *(bf16x4*)(cat + (size_t)row * CATD + cg * 4) = o;
}

// ---------------------------------------------------------------- fused epilogue: W_mix (3 bf16 partials) gate + residual + mask, then LN2
__global__ __launch_bounds__(256) void epi_mix_ln2(
    const bf16* __restrict__ P0, const bf16* __restrict__ P1,
    const bf16* __restrict__ P2, const float* __restrict__ bias,
    const bf16* __restrict__ proj, const float* __restrict__ res,
    const float* __restrict__ mask,
    const float* __restrict__ g2, const float* __restrict__ b2v,
    float* __restrict__ out1, bf16* __restrict__ hbuf)
{
    int row = blockIdx.x, tid = threadIdx.x;
    float m = mask[row];
    size_t off = (size_t)row * DD + tid * 4;
    bf16x4 s0 = *(const bf16x4*)(P0 + off);
    bf16x4 s1 = *(const bf16x4*)(P1 + off);
    bf16x4 s2v = *(const bf16x4*)(P2 + off);
    f32x4 bv = ((const f32x4*)bias)[tid];
    bf16x4 g4 = *(const bf16x4*)(proj + (size_t)row * NPROJ + tid * 4);
    f32x4 rv = ((const f32x4*)(res + (size_t)row * DD))[tid];
    f32x4 v;
    #pragma unroll
    for (int q = 0; q < 4; q++) {
        float sg = 1.0f / (1.0f + __expf(-(float)g4[q]));
        float sv = (float)s0[q] + (float)s1[q] + (float)s2v[q] + bv[q];
        v[q] = (rv[q] + sg * sv) * m;
    }
    ((f32x4*)(out1 + (size_t)row * DD))[tid] = v;
    // LN2
    float s = v[0] + v[1] + v[2] + v[3];
    float s2 = v[0]*v[0] + v[1]*v[1] + v[2]*v[2] + v[3]*v[3];
    #pragma unroll
    for (int off2 = 32; off2 > 0; off2 >>= 1) {
        s  += __shfl_xor(s,  off2, 64);
        s2 += __shfl_xor(s2, off2, 64);
    }
    __shared__ float rs[4], rs2[4];
    int wid = tid >> 6;
    if ((tid & 63) == 0) { rs[wid] = s; rs2[wid] = s2; }
    __syncthreads();
    s  = rs[0] + rs[1] + rs[2] + rs[3];
    s2 = rs2[0] + rs2[1] + rs2[2] + rs2[3];
    float mean = s * (1.0f / DD);
    float var  = s2 * (1.0f / DD) - mean * mean;
    float rstd = rsqrtf(var + 1e-5f);
    f32x4 gg = ((const f32x4*)g2)[tid];
    f32x4 bb = ((const f32x4*)b2v)[tid];
    bf16x4 h;
    #pragma unroll
    for (int q = 0; q < 4; q++)
        h[q] = (bf16)((v[q] - mean) * rstd * gg[q] + bb[q]);
    ((bf16x4*)(hbuf + (size_t)row * DD))[tid] = h;
}

// ---------------------------------------------------------------- final epilogue: out = (out1 + sum 4 bf16 partials + b2) * mask
__global__ __launch_bounds__(256) void epi_w2(
    float* __restrict__ d_out, const float* __restrict__ out1,
    const bf16* __restrict__ P0, const bf16* __restrict__ P1,
    const bf16* __restrict__ P2, const bf16* __restrict__ P3,
    const float* __restrict__ bias, const float* __restrict__ mask)
{
    int id = blockIdx.x * 256 + threadIdx.x;    // over MROWS*DD/4
    int row = id >> 8;                          // 256 f32x4 per row
    float m = mask[row];
    bf16x4 a0 = ((const bf16x4*)P0)[id];
    bf16x4 a1 = ((const bf16x4*)P1)[id];
    bf16x4 a2 = ((const bf16x4*)P2)[id];
    bf16x4 a3 = ((const bf16x4*)P3)[id];
    f32x4 r = ((const f32x4*)out1)[id];
    f32x4 b = ((const f32x4*)bias)[id & 255];
    f32x4 o;
    #pragma unroll
    for (int q = 0; q < 4; q++) {
        float sv = (float)a0[q] + (float)a1[q] + (float)a2[q] + (float)a3[q];
        o[q] = (r[q] + sv + b[q]) * m;
    }
    ((f32x4*)d_out)[id] = o;
}

// ---------------------------------------------------------------- fused dwconv (both kernels, 2 rows/thread, vectorized)
__global__ __launch_bounds__(256) void dwconv_fused(
    const bf16* __restrict__ x,
    const float* __restrict__ w_t, const float* __restrict__ b_t,
    const float* __restrict__ w_p, const float* __restrict__ b_p,
    bf16* __restrict__ cat)
{
    int id = blockIdx.x * 256 + threadIdx.x;    // over (MROWS/2)*128
    int cg = id & 127, rp = id >> 7;
    int c0 = cg * 8;
    int row0 = rp * 2;
    int t0 = row0 & (TT - 1);
    bf16x8 xw[16];
    #pragma unroll
    for (int j = 0; j < 16; j++) {
        int t = t0 - 14 + j;
        if (t >= 0)
            xw[j] = *(const bf16x8*)(x + (size_t)(row0 - 14 + j) * DD + c0);
        else
            #pragma unroll
            for (int q = 0; q < 8; q++) xw[j][q] = (bf16)0.f;
    }
    float y15[2][8], y3[2][8];
    #pragma unroll
    for (int q = 0; q < 8; q++) {
        float bp = b_p[c0 + q], bt = b_t[c0 + q];
        y15[0][q] = bp; y15[1][q] = bp;
        y3[0][q] = bt;  y3[1][q] = bt;
    }
    #pragma unroll
    for (int i = 0; i < 15; i++) {
        float wp[8];
        #pragma unroll
        for (int q = 0; q < 8; q++) wp[q] = w_p[(c0 + q) * 15 + i];
        #pragma unroll
        for (int rr = 0; rr < 2; rr++)
            #pragma unroll
            for (int q = 0; q < 8; q++)
                y15[rr][q] = fmaf(wp[q], (float)xw[rr + i][q], y15[rr][q]);
    }
    #pragma unroll
    for (int i = 0; i < 3; i++) {
        float wt[8];
        #pragma unroll
        for (int q = 0; q < 8; q++) wt[q] = w_t[(c0 + q) * 3 + i];
        #pragma unroll
        for (int rr = 0; rr < 2; rr++)
            #pragma unroll
            for (int q = 0; q < 8; q++)
                y3[rr][q] = fmaf(wt[q], (float)xw[rr + 12 + i][q], y3[rr][q]);
    }
    #pragma unroll
    for (int rr = 0; rr < 2; rr++) {
        bf16x8 o3, o15;
        #pragma unroll
        for (int q = 0; q < 8; q++) { o3[q] = (bf16)y3[rr][q]; o15[q] = (bf16)y15[rr][q]; }
        *(bf16x8*)(cat + (size_t)(row0 + rr) * CATD + DD + c0)     = o3;
        *(bf16x8*)(cat + (size_t)(row0 + rr) * CATD + 2 * DD + c0) = o15;
    }
}

// ---------------------------------------------------------------- attention
__device__ __forceinline__ float phi_f(float x) {
    return x > 0.f ? x + 1.f : __expf(x);   // elu(x)+1
}

// Phase A: per-(b,h,chunk) local sums, LDS-resident. One wave/block, lane==t.
__global__ __launch_bounds__(64) void attn_sums(
    const bf16* __restrict__ proj, const float* __restrict__ mask,
    float* __restrict__ kvsum, float* __restrict__ kssum)
{
    int blk = blockIdx.x;              // bh*NCH + c
    int c  = blk & (NCH - 1);
    int bh = blk >> 5;
    int b  = bh >> 4, hh = bh & (HH - 1);
    int lane = threadIdx.x;
    __shared__ float ks[CHUNK][32], vs[CHUNK][32];
    int row0 = b * TT + c * CHUNK;
    {
        int row = row0 + lane;
        float m = mask[row];
        const bf16* kp = proj + (size_t)row * NPROJ + DD + INNERD + hh * 32;
        const bf16* vp = kp + INNERD;
        #pragma unroll
        for (int s = 0; s < 4; s++) {
            bf16x8 k8 = *(const bf16x8*)(kp + s * 8);
            bf16x8 v8 = *(const bf16x8*)(vp + s * 8);
            #pragma unroll
            for (int q = 0; q < 8; q++) {
                ks[lane][s * 8 + q] = phi_f((float)k8[q]) * m;
                vs[lane][s * 8 + q] = (float)v8[q] * m;
            }
        }
    }
    __syncthreads();
    int e = lane & 31, d0 = (lane >> 5) * 16;
    float kv[16], ksl[16];
    #pragma unroll
    for (int j = 0; j < 16; j++) { kv[j] = 0.f; ksl[j] = 0.f; }
    for (int t = 0; t < CHUNK; t++) {
        float ve = vs[t][e];
        f32x4 kr[4];
        #pragma unroll
        for (int s = 0; s < 4; s++) kr[s] = *(const f32x4*)&ks[t][d0 + s * 4];
        #pragma unroll
        for (int j = 0; j < 16; j++) {
            float kval = kr[j >> 2][j & 3];
            kv[j] = fmaf(kval, ve, kv[j]);
            ksl[j] += kval;
        }
    }
    size_t base = (size_t)blk * 1024;
    #pragma unroll
    for (int j = 0; j < 16; j++)
        kvsum[base + (size_t)(d0 + j) * 32 + e] = kv[j];
    if (e == 0) {
        #pragma unroll
        for (int j = 0; j < 16; j++)
            kssum[blk * 32 + d0 + j] = ksl[j];
    }
}

// Phase B: exclusive prefix over chunks, per (b,h).
__global__ __launch_bounds__(256) void attn_prefix(
    const float* __restrict__ kvsum, const float* __restrict__ kssum,
    float* __restrict__ kvpref, float* __restrict__ kspref)
{
    int bh = blockIdx.x;
    int tid = threadIdx.x;
    float run[4] = {0.f, 0.f, 0.f, 0.f};
    for (int c = 0; c < NCH; c++) {
        size_t base = (size_t)(bh * NCH + c) * 1024 + tid * 4;
        #pragma unroll
        for (int q = 0; q < 4; q++) {
            kvpref[base + q] = run[q];
            run[q] += kvsum[base + q];
        }
    }
    if (tid < 32) {
        float r = 0.f;
        for (int c = 0; c < NCH; c++) {
            kspref[(bh * NCH + c) * 32 + tid] = r;
            r += kssum[(bh * NCH + c) * 32 + tid];
        }
    }
}

// Phase C: in-chunk scan, LDS-resident.
__global__ __launch_bounds__(64) void attn_scan(
    const bf16* __restrict__ proj, const float* __restrict__ mask,
    const float* __restrict__ kvpref, const float* __restrict__ kspref,
    bf16* __restrict__ attn_out)
{
    int blk = blockIdx.x;
    int c  = blk & (NCH - 1);
    int bh = blk >> 5;
    int b  = bh >> 4, hh = bh & (HH - 1);
    int lane = threadIdx.x;
    __shared__ float qs[CHUNK][32], ks[CHUNK][32], vs[CHUNK][32];
    __shared__ float ms[CHUNK];
    int row0 = b * TT + c * CHUNK;
    {
        int row = row0 + lane;
        float m = mask[row];
        ms[lane] = m;
        const bf16* qp = proj + (size_t)row * NPROJ + DD + hh * 32;
        const bf16* kp = qp + INNERD;
        const bf16* vp = kp + INNERD;
        #pragma unroll
        for (int s = 0; s < 4; s++) {
            bf16x8 q8 = *(const bf16x8*)(qp + s * 8);
            bf16x8 k8 = *(const bf16x8*)(kp + s * 8);
            bf16x8 v8 = *(const bf16x8*)(vp + s * 8);
            #pragma unroll
            for (int q = 0; q < 8; q++) {
                qs[lane][s * 8 + q] = phi_f((float)q8[q]) * m;
                ks[lane][s * 8 + q] = phi_f((float)k8[q]) * m;
                vs[lane][s * 8 + q] = (float)v8[q] * m;
            }
        }
    }
    int e = lane & 31, d0 = (lane >> 5) * 16;
    float kv[16], ksl[16];
    size_t base = (size_t)blk * 1024;
    #pragma unroll
    for (int j = 0; j < 16; j++) kv[j] = kvpref[base + (size_t)(d0 + j) * 32 + e];
    #pragma unroll
    for (int j = 0; j < 16; j++) ksl[j] = kspref[blk * 32 + d0 + j];
    __syncthreads();
    for (int t = 0; t < CHUNK; t++) {
        float ve = vs[t][e];
        f32x4 kr[4], qr[4];
        #pragma unroll
        for (int s = 0; s < 4; s++) kr[s] = *(const f32x4*)&ks[t][d0 + s * 4];
        #pragma unroll
        for (int s = 0; s < 4; s++) qr[s] = *(const f32x4*)&qs[t][d0 + s * 4];
        float num0 = 0.f, num1 = 0.f, den0 = 0.f, den1 = 0.f;
        #pragma unroll
        for (int j = 0; j < 16; j++) {
            float kval = kr[j >> 2][j & 3], qval = qr[j >> 2][j & 3];
            kv[j]  = fmaf(kval, ve, kv[j]);   // inclusive cumsum
            ksl[j] += kval;
            if (j & 1) { num1 = fmaf(qval, kv[j], num1); den1 = fmaf(qval, ksl[j], den1); }
            else       { num0 = fmaf(qval, kv[j], num0); den0 = fmaf(qval, ksl[j], den0); }
        }
        float num = num0 + num1, den = den0 + den1;
        num += __shfl_xor(num, 32, 64);
        den += __shfl_xor(den, 32, 64);
        if (lane < 32)
            attn_out[(size_t)(row0 + t) * INNERD + hh * 32 + e] =
                (bf16)(num / (den + 1e-6f) * ms[t]);
    }
}

// ---------------------------------------------------------------- launch
extern "C" void kernel_launch(void* const* d_in, const int* in_sizes, int n_in,
                              void* d_out, int out_size, void* d_ws, size_t ws_size,
                              hipStream_t stream)
{
    const float* inputs = (const float*)d_in[0];
    const float* mask   = (const float*)d_in[1];
    const float* ln1_g  = (const float*)d_in[2];
    const float* ln1_b  = (const float*)d_in[3];
    const float* W_in   = (const float*)d_in[4];
    const float* b_in   = (const float*)d_in[5];
    const float* W_c    = (const float*)d_in[6];
    const float* b_c    = (const float*)d_in[7];
    const float* w_t    = (const float*)d_in[8];
    const float* b_t    = (const float*)d_in[9];
    const float* w_p    = (const float*)d_in[10];
    const float* b_p    = (const float*)d_in[11];
    const float* W_mix  = (const float*)d_in[12];
    const float* b_mix  = (const float*)d_in[13];
    const float* ln2_g  = (const float*)d_in[14];
    const float* ln2_b  = (const float*)d_in[15];
    const float* W1     = (const float*)d_in[16];
    const float* b1     = (const float*)d_in[17];
    const float* W2     = (const float*)d_in[18];
    const float* b2     = (const float*)d_in[19];
    float* out = (float*)d_out;

    // workspace layout (bytes). ffn1 aliases [normed|proj|attnb] (dead by W1).
    // attn kv scratch aliases out1 (dead until epi_mix_ln2).
    // Split-K partial buffers (non-atomic, fully overwritten by their GEMM):
    //   W_c  (fp32 x2): d_out, out1-region
    //   W_mix(bf16 x3): d_out (2 partials), hbuf-region
    //   W2   (bf16 x4): cat-region (3 partials), hbuf-region
    char* p = (char*)d_ws;
    bf16* normed = (bf16*)p;  p += (size_t)MROWS * DD * 2;
    bf16* proj   = (bf16*)p;  p += (size_t)MROWS * NPROJ * 2;
    bf16* attnb  = (bf16*)p;  p += (size_t)MROWS * INNERD * 2;
    bf16* cat    = (bf16*)p;  p += (size_t)MROWS * CATD * 2;
    float* out1  = (float*)p; p += (size_t)MROWS * DD * 4;
    bf16* hbuf   = (bf16*)p;  p += (size_t)MROWS * DD * 2;
    bf16* wt_in  = (bf16*)p;  p += (size_t)NPROJ * DD * 2;
    bf16* wt_c   = (bf16*)p;  p += (size_t)DD * INNERD * 2;
    bf16* wt_mix = (bf16*)p;  p += (size_t)DD * CATD * 2;
    bf16* wt1    = (bf16*)p;  p += (size_t)FFD * DD * 2;
    bf16* wt2    = (bf16*)p;  p += (size_t)DD * FFD * 2;
    bf16* ffn1   = (bf16*)d_ws;                  // alias [normed|proj|attnb]
    float* kvsum = out1;                         // alias out1 region (attn)
    float* kvpref= kvsum  + (size_t)BH * NCH * 1024;
    float* kssum = kvpref + (size_t)BH * NCH * 1024;
    float* kspref= kssum  + (size_t)BH * NCH * 32;
    // split-K partials
    float* c_p0  = (float*)d_out;
    float* c_p1  = out1;
    bf16*  m_p0  = (bf16*)d_out;
    bf16*  m_p1  = (bf16*)d_out + (size_t)MROWS * DD;
    bf16*  m_p2  = hbuf;
    bf16*  w2_p0 = cat;
    bf16*  w2_p1 = cat + (size_t)MROWS * DD;
    bf16*  w2_p2 = cat + (size_t)MROWS * DD * 2;
    bf16*  w2_p3 = hbuf;

    // 0. weight transposes fp32(K,N) -> bf16(N,K)
    transpose_cvt<<<dim3(NPROJ/32, DD/32),   256, 0, stream>>>(W_in,  wt_in,  DD,     NPROJ);
    transpose_cvt<<<dim3(DD/32,    INNERD/32),256, 0, stream>>>(W_c,   wt_c,   INNERD, DD);
    transpose_cvt<<<dim3(DD/32,    CATD/32), 256, 0, stream>>>(W_mix, wt_mix, CATD,   DD);
    transpose_cvt<<<dim3(FFD/32,   DD/32),   256, 0, stream>>>(W1,    wt1,    DD,     FFD);
    transpose_cvt<<<dim3(DD/32,    FFD/32),  256, 0, stream>>>(W2,    wt2,    FFD,    DD);

    // 1. LN1 -> bf16
    layernorm_k<<<MROWS, 256, 0, stream>>>(inputs, ln1_g, ln1_b, normed);
    // 2. proj = normed @ W_in + b_in (bf16 out)
    gemm_mfma<0><<<dim3(NPROJ/128, MROWS/128), 256, 0, stream>>>(
        normed, DD, wt_in, DD, b_in, proj, NPROJ, DD, Part4{});
    // 3. chunked causal linear attention -> attnb (M x 512, bf16)
    attn_sums  <<<BH * NCH, 64, 0, stream>>>(proj, mask, kvsum, kssum);
    attn_prefix<<<BH, 256, 0, stream>>>(kvsum, kssum, kvpref, kspref);
    attn_scan  <<<BH * NCH, 64, 0, stream>>>(proj, mask, kvpref, kspref, attnb);
    // 4. fused depthwise causal convs -> cat[:,D:2D], cat[:,2D:3D]
    dwconv_fused<<<(MROWS/2) * 128 / 256, 256, 0, stream>>>(normed, w_t, b_t, w_p, b_p, cat);
    // 5. W_c split-2 fp32 partials, then cat[:,0:D] = bf16(P0+P1+b_c)
    gemm_mfma<5><<<dim3(DD/128, MROWS/128, 2), 256, 0, stream>>>(
        attnb, INNERD, wt_c, INNERD, nullptr, nullptr, DD, INNERD / 2,
        Part4{c_p0, c_p1, nullptr, nullptr});
    epi_wc<<<MROWS * DD / 4 / 256, 256, 0, stream>>>(c_p0, c_p1, b_c, cat);
    // 6. W_mix split-3 bf16 partials
    gemm_mfma<4><<<dim3(DD/128, MROWS/128, 3), 256, 0, stream>>>(
        cat, CATD, wt_mix, CATD, nullptr, nullptr, DD, CATD / 3,
        Part4{m_p0, m_p1, m_p2, nullptr});
    // 7. out1 = (inputs + sigmoid(gate)*(sum P + b_mix))*mask ; hbuf = LN2(out1)
    epi_mix_ln2<<<MROWS, 256, 0, stream>>>(m_p0, m_p1, m_p2, b_mix, proj, inputs,
                                           mask, ln2_g, ln2_b, out1, hbuf);
    // 8. ffn1 = gelu(hbuf @ W1 + b1) (bf16 out; aliases dead normed/proj/attnb)
    gemm_mfma<1><<<dim3(FFD/128, MROWS/128), 256, 0, stream>>>(
        hbuf, DD, wt1, DD, b1, ffn1, FFD, DD, Part4{});
    // 9. W2 split-4 bf16 partials
    gemm_mfma<4><<<dim3(DD/128, MROWS/128, 4), 256, 0, stream>>>(
        ffn1, FFD, wt2, FFD, nullptr, nullptr, DD, FFD / 4,
        Part4{w2_p0, w2_p1, w2_p2, w2_p3});
    // 10. out = (out1 + sum P + b2) * mask
    epi_w2<<<MROWS * DD / 4 / 256, 256, 0, stream>>>(out, out1, w2_p0, w2_p1,
                                                     w2_p2, w2_p3, b2, mask);
}

// Round 7
// 396.343 us; speedup vs baseline: 5.5097x; 1.0754x over previous
//
#include <hip/hip_runtime.h>
#include <math.h>

#define BB 2
#define TT 2048
#define DD 1024
#define HH 16
#define INNERD 512
#define FFD 4096
#define NPROJ 2560     // D + 3*INNER
#define CATD 3072      // 3*D
#define MROWS (BB*TT)  // 4096
#define CHUNK 64
#define NCH (TT/CHUNK) // 32
#define BH 32          // B*H

typedef __bf16 bf16;
typedef __attribute__((ext_vector_type(8))) __bf16 bf16x8;
typedef __attribute__((ext_vector_type(4))) __bf16 bf16x4;
typedef __attribute__((ext_vector_type(4))) float f32x4;

struct Part4 { void* p0; void* p1; void* p2; void* p3; };

// ---------------------------------------------------------------- fused prep:
// blocks [0,4096): LN1 row kernel
// blocks [4096,18432): 32x32 transpose tiles for the 5 weights
__global__ __launch_bounds__(256) void prep_fused(
    const float* __restrict__ inputs, const float* __restrict__ ln1_g,
    const float* __restrict__ ln1_b, bf16* __restrict__ normed,
    const float* __restrict__ W_in,  bf16* __restrict__ wt_in,
    const float* __restrict__ W_c,   bf16* __restrict__ wt_c,
    const float* __restrict__ W_mix, bf16* __restrict__ wt_mix,
    const float* __restrict__ W1,    bf16* __restrict__ wt1,
    const float* __restrict__ W2,    bf16* __restrict__ wt2)
{
    int blk = blockIdx.x, tid = threadIdx.x;
    if (blk < MROWS) {
        // ---- LN1 ----
        int row = blk;
        f32x4 xv = ((const f32x4*)(inputs + (size_t)row * DD))[tid];
        float s = xv[0] + xv[1] + xv[2] + xv[3];
        float s2 = xv[0]*xv[0] + xv[1]*xv[1] + xv[2]*xv[2] + xv[3]*xv[3];
        #pragma unroll
        for (int off = 32; off > 0; off >>= 1) {
            s  += __shfl_xor(s,  off, 64);
            s2 += __shfl_xor(s2, off, 64);
        }
        __shared__ float rs[4], rs2[4];
        int wid = tid >> 6;
        if ((tid & 63) == 0) { rs[wid] = s; rs2[wid] = s2; }
        __syncthreads();
        s  = rs[0] + rs[1] + rs[2] + rs[3];
        s2 = rs2[0] + rs2[1] + rs2[2] + rs2[3];
        float mean = s * (1.0f / DD);
        float var  = s2 * (1.0f / DD) - mean * mean;
        float rstd = rsqrtf(var + 1e-5f);
        f32x4 gv = ((const f32x4*)ln1_g)[tid];
        f32x4 bv = ((const f32x4*)ln1_b)[tid];
        bf16x4 o;
        #pragma unroll
        for (int q = 0; q < 4; q++)
            o[q] = (bf16)((xv[q] - mean) * rstd * gv[q] + bv[q]);
        ((bf16x4*)(normed + (size_t)row * DD))[tid] = o;
        return;
    }
    // ---- transpose fp32(K,N) -> bf16(N,K), 32x32 tiles ----
    int tb = blk - MROWS;
    const float* W; bf16* Wt; int Kd, Nd;
    if      (tb < 2560)  {             W = W_in;  Wt = wt_in;  Kd = 1024; Nd = 2560; }
    else if (tb < 3072)  { tb -= 2560; W = W_c;   Wt = wt_c;   Kd = 512;  Nd = 1024; }
    else if (tb < 6144)  { tb -= 3072; W = W_mix; Wt = wt_mix; Kd = 3072; Nd = 1024; }
    else if (tb < 10240) { tb -= 6144; W = W1;    Wt = wt1;    Kd = 1024; Nd = 4096; }
    else                 { tb -= 10240;W = W2;    Wt = wt2;    Kd = 4096; Nd = 1024; }
    int ntx = Nd >> 5;
    int nb = (tb % ntx) * 32, kb = (tb / ntx) * 32;
    __shared__ float t[32][33];
    int tx = tid & 31, ty = tid >> 5;   // 32 x 8
    #pragma unroll
    for (int r = 0; r < 32; r += 8)
        t[ty + r][tx] = W[(size_t)(kb + ty + r) * Nd + nb + tx];
    __syncthreads();
    #pragma unroll
    for (int r = 0; r < 32; r += 8)
        Wt[(size_t)(nb + ty + r) * Kd + kb + tx] = (bf16)t[tx][ty + r];
}

// ---------------------------------------------------------------- MFMA GEMM, BK=64, 4 blocks/CU
// Grid is (M/128, N/128, z) — m from blockIdx.x so same-A blocks (which
// differ only in n) land on the SAME XCD (linear%8 == bx%8): per-XCD L2
// footprint for N=1024 K-split GEMMs = 1MB A + 2MB B < 4MB.
// EPI 0: +bias -> bf16 Cb      EPI 1: fast-gelu(+bias) -> bf16 Cb
// EPI 4: bf16 partial -> part.p[z] (ldc=DD)
template<int EPI>
__global__ __launch_bounds__(256, 4) void gemm_mfma(
    const bf16* __restrict__ A,  int lda,
    const bf16* __restrict__ Bt, int ldb,
    const float* __restrict__ bias,
    bf16* __restrict__ Cb, int ldc,
    int K, Part4 part)
{
    __shared__ bf16 As[128 * 64];   // chunk-contiguous: 16 chunks of 16rows x 32k
    __shared__ bf16 Bs[128 * 64];
    const int tid  = threadIdx.x;
    const int wave = tid >> 6, lane = tid & 63;
    const int m0 = blockIdx.x * 128, n0 = blockIdx.y * 128;   // grid-transposed
    const int koff = blockIdx.z * K;
    A  += koff;
    Bt += koff;
    const int wr = wave >> 1, wc = wave & 1;
    const int lrow = lane >> 2;          // staging row within 16-row chunk
    const int lcol = (lane & 3) * 8;     // staging k offset within 32-k half
    const int fm = lane & 15;            // fragment m/n within 16-tile
    const int fk = (lane >> 4) * 8;      // fragment k offset

    f32x4 acc[4][4];
    #pragma unroll
    for (int i = 0; i < 4; i++)
        #pragma unroll
        for (int j = 0; j < 4; j++)
            acc[i][j] = (f32x4){0.f, 0.f, 0.f, 0.f};

    for (int k0 = 0; k0 < K; k0 += 64) {
        #pragma unroll
        for (int r = 0; r < 4; r++) {
            int c  = r * 4 + wave;            // chunk 0..15
            int rc = c >> 1, kh = c & 1;      // row-chunk, k-half
            const bf16* ga = A  + (size_t)(m0 + rc * 16 + lrow) * lda + k0 + kh * 32 + lcol;
            const bf16* gb = Bt + (size_t)(n0 + rc * 16 + lrow) * ldb + k0 + kh * 32 + lcol;
            __builtin_amdgcn_global_load_lds(
                (const __attribute__((address_space(1))) void*)ga,
                (__attribute__((address_space(3))) void*)(As + c * 512), 16, 0, 0);
            __builtin_amdgcn_global_load_lds(
                (const __attribute__((address_space(1))) void*)gb,
                (__attribute__((address_space(3))) void*)(Bs + c * 512), 16, 0, 0);
        }
        __syncthreads();
        #pragma unroll
        for (int ks = 0; ks < 2; ks++) {
            bf16x8 af[4], bfv[4];
            #pragma unroll
            for (int i = 0; i < 4; i++)
                af[i] = *(const bf16x8*)(As + (wr * 4 + i) * 1024 + ks * 512 + fm * 32 + fk);
            #pragma unroll
            for (int j = 0; j < 4; j++)
                bfv[j] = *(const bf16x8*)(Bs + (wc * 4 + j) * 1024 + ks * 512 + fm * 32 + fk);
            #pragma unroll
            for (int i = 0; i < 4; i++)
                #pragma unroll
                for (int j = 0; j < 4; j++)
                    acc[i][j] = __builtin_amdgcn_mfma_f32_16x16x32_bf16(
                        af[i], bfv[j], acc[i][j], 0, 0, 0);
        }
        __syncthreads();
    }

    void* psel = nullptr;
    if constexpr (EPI == 4) {
        int z = blockIdx.z;
        psel = (z == 0) ? part.p0 : (z == 1) ? part.p1 : (z == 2) ? part.p2 : part.p3;
    }

    #pragma unroll
    for (int i = 0; i < 4; i++) {
        int mbase = m0 + wr * 64 + i * 16 + (lane >> 4) * 4;
        #pragma unroll
        for (int j = 0; j < 4; j++) {
            int col = n0 + wc * 64 + j * 16 + (lane & 15);
            float bv = 0.f;
            if constexpr (EPI == 0 || EPI == 1) bv = bias[col];
            #pragma unroll
            for (int r = 0; r < 4; r++) {
                int row = mbase + r;
                float v = acc[i][j][r] + bv;
                if constexpr (EPI == 0) {
                    Cb[(size_t)row * ldc + col] = (bf16)v;
                } else if constexpr (EPI == 1) {
                    // fast gelu: x * sigmoid(1.5957691x + 0.07135502x^3)
                    float z2 = v * (1.5957691f + 0.07135502f * v * v);
                    v = v / (1.0f + __expf(-z2));
                    Cb[(size_t)row * ldc + col] = (bf16)v;
                } else {
                    ((bf16*)psel)[(size_t)row * DD + col] = (bf16)v;
                }
            }
        }
    }
}

// ---------------------------------------------------------------- epilogue: cat[:,0:D] = bf16(P0 + P1 + b_c)
__global__ __launch_bounds__(256) void epi_wc(
    const bf16* __restrict__ P0, const bf16* __restrict__ P1,
    const float* __restrict__ bias, bf16* __restrict__ cat)
{
    int id = blockIdx.x * 256 + threadIdx.x;    // over MROWS*DD/4
    int row = id >> 8, cg = id & 255;
    bf16x4 s0 = ((const bf16x4*)P0)[id];
    bf16x4 s1 = ((const bf16x4*)P1)[id];
    f32x4 b  = ((const f32x4*)bias)[cg];
    bf16x4 o;
    #pragma unroll
    for (int q = 0; q < 4; q++) o[q] = (bf16)((float)s0[q] + (float)s1[q] + b[q]);
    *(bf16x4*)(cat + (size_t)row * CATD + cg * 4) = o;
}

// ---------------------------------------------------------------- fused epilogue: W_mix (3 bf16 partials) gate + residual + mask, then LN2
__global__ __launch_bounds__(256) void epi_mix_ln2(
    const bf16* __restrict__ P0, const bf16* __restrict__ P1,
    const bf16* __restrict__ P2, const float* __restrict__ bias,
    const bf16* __restrict__ proj, const float* __restrict__ res,
    const float* __restrict__ mask,
    const float* __restrict__ g2, const float* __restrict__ b2v,
    float* __restrict__ out1, bf16* __restrict__ hbuf)
{
    int row = blockIdx.x, tid = threadIdx.x;
    float m = mask[row];
    size_t off = (size_t)row * DD + tid * 4;
    bf16x4 s0 = *(const bf16x4*)(P0 + off);
    bf16x4 s1 = *(const bf16x4*)(P1 + off);
    bf16x4 s2v = *(const bf16x4*)(P2 + off);
    f32x4 bv = ((const f32x4*)bias)[tid];
    bf16x4 g4 = *(const bf16x4*)(proj + (size_t)row * NPROJ + tid * 4);
    f32x4 rv = ((const f32x4*)(res + (size_t)row * DD))[tid];
    f32x4 v;
    #pragma unroll
    for (int q = 0; q < 4; q++) {
        float sg = 1.0f / (1.0f + __expf(-(float)g4[q]));
        float sv = (float)s0[q] + (float)s1[q] + (float)s2v[q] + bv[q];
        v[q] = (rv[q] + sg * sv) * m;
    }
    ((f32x4*)(out1 + (size_t)row * DD))[tid] = v;
    // LN2
    float s = v[0] + v[1] + v[2] + v[3];
    float s2 = v[0]*v[0] + v[1]*v[1] + v[2]*v[2] + v[3]*v[3];
    #pragma unroll
    for (int off2 = 32; off2 > 0; off2 >>= 1) {
        s  += __shfl_xor(s,  off2, 64);
        s2 += __shfl_xor(s2, off2, 64);
    }
    __shared__ float rs[4], rs2[4];
    int wid = tid >> 6;
    if ((tid & 63) == 0) { rs[wid] = s; rs2[wid] = s2; }
    __syncthreads();
    s  = rs[0] + rs[1] + rs[2] + rs[3];
    s2 = rs2[0] + rs2[1] + rs2[2] + rs2[3];
    float mean = s * (1.0f / DD);
    float var  = s2 * (1.0f / DD) - mean * mean;
    float rstd = rsqrtf(var + 1e-5f);
    f32x4 gg = ((const f32x4*)g2)[tid];
    f32x4 bb = ((const f32x4*)b2v)[tid];
    bf16x4 h;
    #pragma unroll
    for (int q = 0; q < 4; q++)
        h[q] = (bf16)((v[q] - mean) * rstd * gg[q] + bb[q]);
    ((bf16x4*)(hbuf + (size_t)row * DD))[tid] = h;
}

// ---------------------------------------------------------------- final epilogue: out = (out1 + sum 4 bf16 partials + b2) * mask
__global__ __launch_bounds__(256) void epi_w2(
    float* __restrict__ d_out, const float* __restrict__ out1,
    const bf16* __restrict__ P0, const bf16* __restrict__ P1,
    const bf16* __restrict__ P2, const bf16* __restrict__ P3,
    const float* __restrict__ bias, const float* __restrict__ mask)
{
    int id = blockIdx.x * 256 + threadIdx.x;    // over MROWS*DD/4
    int row = id >> 8;                          // 256 f32x4 per row
    float m = mask[row];
    bf16x4 a0 = ((const bf16x4*)P0)[id];
    bf16x4 a1 = ((const bf16x4*)P1)[id];
    bf16x4 a2 = ((const bf16x4*)P2)[id];
    bf16x4 a3 = ((const bf16x4*)P3)[id];
    f32x4 r = ((const f32x4*)out1)[id];
    f32x4 b = ((const f32x4*)bias)[id & 255];
    f32x4 o;
    #pragma unroll
    for (int q = 0; q < 4; q++) {
        float sv = (float)a0[q] + (float)a1[q] + (float)a2[q] + (float)a3[q];
        o[q] = (r[q] + sv + b[q]) * m;
    }
    ((f32x4*)d_out)[id] = o;
}

// ---------------------------------------------------------------- attention helpers
__device__ __forceinline__ float phi_f(float x) {
    return x > 0.f ? x + 1.f : __expf(x);   // elu(x)+1
}

// ---------------------------------------------------------------- mid fused:
// blocks [0,1024): dwconv (both kernels, 2 rows/thread, vectorized)
// blocks [1024,1536): attn phase A local sums — waves 0,1 each own one chunk
// (wave-synchronous LDS, no barrier; waves 2,3 exit)
__global__ __launch_bounds__(256) void mid_fused(
    const bf16* __restrict__ x,
    const float* __restrict__ w_t, const float* __restrict__ b_t,
    const float* __restrict__ w_p, const float* __restrict__ b_p,
    bf16* __restrict__ cat,
    const bf16* __restrict__ proj, const float* __restrict__ mask,
    float* __restrict__ kvsum, float* __restrict__ kssum)
{
    __shared__ float s_ks[2][CHUNK][32], s_vs[2][CHUNK][32];   // 32 KB
    int blk = blockIdx.x, tid = threadIdx.x;
    if (blk < 1024) {
        // ---- dwconv ----
        int id = blk * 256 + tid;                // over (MROWS/2)*128
        int cg = id & 127, rp = id >> 7;
        int c0 = cg * 8;
        int row0 = rp * 2;
        int t0 = row0 & (TT - 1);
        bf16x8 xw[16];
        #pragma unroll
        for (int j = 0; j < 16; j++) {
            int t = t0 - 14 + j;
            if (t >= 0)
                xw[j] = *(const bf16x8*)(x + (size_t)(row0 - 14 + j) * DD + c0);
            else
                #pragma unroll
                for (int q = 0; q < 8; q++) xw[j][q] = (bf16)0.f;
        }
        float y15[2][8], y3[2][8];
        #pragma unroll
        for (int q = 0; q < 8; q++) {
            float bp = b_p[c0 + q], bt = b_t[c0 + q];
            y15[0][q] = bp; y15[1][q] = bp;
            y3[0][q] = bt;  y3[1][q] = bt;
        }
        #pragma unroll
        for (int i = 0; i < 15; i++) {
            float wp[8];
            #pragma unroll
            for (int q = 0; q < 8; q++) wp[q] = w_p[(c0 + q) * 15 + i];
            #pragma unroll
            for (int rr = 0; rr < 2; rr++)
                #pragma unroll
                for (int q = 0; q < 8; q++)
                    y15[rr][q] = fmaf(wp[q], (float)xw[rr + i][q], y15[rr][q]);
        }
        #pragma unroll
        for (int i = 0; i < 3; i++) {
            float wt[8];
            #pragma unroll
            for (int q = 0; q < 8; q++) wt[q] = w_t[(c0 + q) * 3 + i];
            #pragma unroll
            for (int rr = 0; rr < 2; rr++)
                #pragma unroll
                for (int q = 0; q < 8; q++)
                    y3[rr][q] = fmaf(wt[q], (float)xw[rr + 12 + i][q], y3[rr][q]);
        }
        #pragma unroll
        for (int rr = 0; rr < 2; rr++) {
            bf16x8 o3, o15;
            #pragma unroll
            for (int q = 0; q < 8; q++) { o3[q] = (bf16)y3[rr][q]; o15[q] = (bf16)y15[rr][q]; }
            *(bf16x8*)(cat + (size_t)(row0 + rr) * CATD + DD + c0)     = o3;
            *(bf16x8*)(cat + (size_t)(row0 + rr) * CATD + 2 * DD + c0) = o15;
        }
        return;
    }
    // ---- attn phase A ----
    int w = tid >> 6;
    if (w >= 2) return;
    int lane = tid & 63;
    int ci = (blk - 1024) * 2 + w;     // chunk id 0..1023 == bh*NCH + c
    int c  = ci & (NCH - 1);
    int bh = ci >> 5;
    int b  = bh >> 4, hh = bh & (HH - 1);
    float (*ks)[32] = s_ks[w];
    float (*vs)[32] = s_vs[w];
    int row0 = b * TT + c * CHUNK;
    {
        int row = row0 + lane;
        float m = mask[row];
        const bf16* kp = proj + (size_t)row * NPROJ + DD + INNERD + hh * 32;
        const bf16* vp = kp + INNERD;
        #pragma unroll
        for (int s = 0; s < 4; s++) {
            bf16x8 k8 = *(const bf16x8*)(kp + s * 8);
            bf16x8 v8 = *(const bf16x8*)(vp + s * 8);
            #pragma unroll
            for (int q = 0; q < 8; q++) {
                ks[lane][s * 8 + q] = phi_f((float)k8[q]) * m;
                vs[lane][s * 8 + q] = (float)v8[q] * m;
            }
        }
    }
    // wave-synchronous: same wave wrote, same wave reads — compiler inserts lgkmcnt
    int e = lane & 31, d0 = (lane >> 5) * 16;
    float kv[16], ksl[16];
    #pragma unroll
    for (int j = 0; j < 16; j++) { kv[j] = 0.f; ksl[j] = 0.f; }
    for (int t = 0; t < CHUNK; t++) {
        float ve = vs[t][e];
        f32x4 kr[4];
        #pragma unroll
        for (int s = 0; s < 4; s++) kr[s] = *(const f32x4*)&ks[t][d0 + s * 4];
        #pragma unroll
        for (int j = 0; j < 16; j++) {
            float kval = kr[j >> 2][j & 3];
            kv[j] = fmaf(kval, ve, kv[j]);
            ksl[j] += kval;
        }
    }
    size_t base = (size_t)ci * 1024;
    #pragma unroll
    for (int j = 0; j < 16; j++)
        kvsum[base + (size_t)(d0 + j) * 32 + e] = kv[j];
    if (e == 0) {
        #pragma unroll
        for (int j = 0; j < 16; j++)
            kssum[ci * 32 + d0 + j] = ksl[j];
    }
}

// Phase B: exclusive prefix over chunks, per (b,h).
__global__ __launch_bounds__(256) void attn_prefix(
    const float* __restrict__ kvsum, const float* __restrict__ kssum,
    float* __restrict__ kvpref, float* __restrict__ kspref)
{
    int bh = blockIdx.x;
    int tid = threadIdx.x;
    float run[4] = {0.f, 0.f, 0.f, 0.f};
    for (int c = 0; c < NCH; c++) {
        size_t base = (size_t)(bh * NCH + c) * 1024 + tid * 4;
        #pragma unroll
        for (int q = 0; q < 4; q++) {
            kvpref[base + q] = run[q];
            run[q] += kvsum[base + q];
        }
    }
    if (tid < 32) {
        float r = 0.f;
        for (int c = 0; c < NCH; c++) {
            kspref[(bh * NCH + c) * 32 + tid] = r;
            r += kssum[(bh * NCH + c) * 32 + tid];
        }
    }
}

// Phase C: in-chunk scan, LDS-resident.
__global__ __launch_bounds__(64) void attn_scan(
    const bf16* __restrict__ proj, const float* __restrict__ mask,
    const float* __restrict__ kvpref, const float* __restrict__ kspref,
    bf16* __restrict__ attn_out)
{
    int blk = blockIdx.x;
    int c  = blk & (NCH - 1);
    int bh = blk >> 5;
    int b  = bh >> 4, hh = bh & (HH - 1);
    int lane = threadIdx.x;
    __shared__ float qs[CHUNK][32], ks[CHUNK][32], vs[CHUNK][32];
    __shared__ float ms[CHUNK];
    int row0 = b * TT + c * CHUNK;
    {
        int row = row0 + lane;
        float m = mask[row];
        ms[lane] = m;
        const bf16* qp = proj + (size_t)row * NPROJ + DD + hh * 32;
        const bf16* kp = qp + INNERD;
        const bf16* vp = kp + INNERD;
        #pragma unroll
        for (int s = 0; s < 4; s++) {
            bf16x8 q8 = *(const bf16x8*)(qp + s * 8);
            bf16x8 k8 = *(const bf16x8*)(kp + s * 8);
            bf16x8 v8 = *(const bf16x8*)(vp + s * 8);
            #pragma unroll
            for (int q = 0; q < 8; q++) {
                qs[lane][s * 8 + q] = phi_f((float)q8[q]) * m;
                ks[lane][s * 8 + q] = phi_f((float)k8[q]) * m;
                vs[lane][s * 8 + q] = (float)v8[q] * m;
            }
        }
    }
    int e = lane & 31, d0 = (lane >> 5) * 16;
    float kv[16], ksl[16];
    size_t base = (size_t)blk * 1024;
    #pragma unroll
    for (int j = 0; j < 16; j++) kv[j] = kvpref[base + (size_t)(d0 + j) * 32 + e];
    #pragma unroll
    for (int j = 0; j < 16; j++) ksl[j] = kspref[blk * 32 + d0 + j];
    __syncthreads();
    for (int t = 0; t < CHUNK; t++) {
        float ve = vs[t][e];
        f32x4 kr[4], qr[4];
        #pragma unroll
        for (int s = 0; s < 4; s++) kr[s] = *(const f32x4*)&ks[t][d0 + s * 4];
        #pragma unroll
        for (int s = 0; s < 4; s++) qr[s] = *(const f32x4*)&qs[t][d0 + s * 4];
        float num0 = 0.f, num1 = 0.f, den0 = 0.f, den1 = 0.f;
        #pragma unroll
        for (int j = 0; j < 16; j++) {
            float kval = kr[j >> 2][j & 3], qval = qr[j >> 2][j & 3];
            kv[j]  = fmaf(kval, ve, kv[j]);   // inclusive cumsum
            ksl[j] += kval;
            if (j & 1) { num1 = fmaf(qval, kv[j], num1); den1 = fmaf(qval, ksl[j], den1); }
            else       { num0 = fmaf(qval, kv[j], num0); den0 = fmaf(qval, ksl[j], den0); }
        }
        float num = num0 + num1, den = den0 + den1;
        num += __shfl_xor(num, 32, 64);
        den += __shfl_xor(den, 32, 64);
        if (lane < 32)
            attn_out[(size_t)(row0 + t) * INNERD + hh * 32 + e] =
                (bf16)(num / (den + 1e-6f) * ms[t]);
    }
}

// ---------------------------------------------------------------- launch
extern "C" void kernel_launch(void* const* d_in, const int* in_sizes, int n_in,
                              void* d_out, int out_size, void* d_ws, size_t ws_size,
                              hipStream_t stream)
{
    const float* inputs = (const float*)d_in[0];
    const float* mask   = (const float*)d_in[1];
    const float* ln1_g  = (const float*)d_in[2];
    const float* ln1_b  = (const float*)d_in[3];
    const float* W_in   = (const float*)d_in[4];
    const float* b_in   = (const float*)d_in[5];
    const float* W_c    = (const float*)d_in[6];
    const float* b_c    = (const float*)d_in[7];
    const float* w_t    = (const float*)d_in[8];
    const float* b_t    = (const float*)d_in[9];
    const float* w_p    = (const float*)d_in[10];
    const float* b_p    = (const float*)d_in[11];
    const float* W_mix  = (const float*)d_in[12];
    const float* b_mix  = (const float*)d_in[13];
    const float* ln2_g  = (const float*)d_in[14];
    const float* ln2_b  = (const float*)d_in[15];
    const float* W1     = (const float*)d_in[16];
    const float* b1     = (const float*)d_in[17];
    const float* W2     = (const float*)d_in[18];
    const float* b2     = (const float*)d_in[19];
    float* out = (float*)d_out;

    // workspace layout (bytes). ffn1 aliases [normed|proj|attnb] (dead by W1).
    // attn kv scratch aliases out1 (dead until epi_mix_ln2).
    // Split-K bf16 partials (non-atomic, fully overwritten by their GEMM):
    //   W_c : d_out, out1-region
    //   W_mix: d_out (2 partials), hbuf-region
    //   W2  : cat-region (3 partials), hbuf-region
    char* p = (char*)d_ws;
    bf16* normed = (bf16*)p;  p += (size_t)MROWS * DD * 2;
    bf16* proj   = (bf16*)p;  p += (size_t)MROWS * NPROJ * 2;
    bf16* attnb  = (bf16*)p;  p += (size_t)MROWS * INNERD * 2;
    bf16* cat    = (bf16*)p;  p += (size_t)MROWS * CATD * 2;
    float* out1  = (float*)p; p += (size_t)MROWS * DD * 4;
    bf16* hbuf   = (bf16*)p;  p += (size_t)MROWS * DD * 2;
    bf16* wt_in  = (bf16*)p;  p += (size_t)NPROJ * DD * 2;
    bf16* wt_c   = (bf16*)p;  p += (size_t)DD * INNERD * 2;
    bf16* wt_mix = (bf16*)p;  p += (size_t)DD * CATD * 2;
    bf16* wt1    = (bf16*)p;  p += (size_t)FFD * DD * 2;
    bf16* wt2    = (bf16*)p;  p += (size_t)DD * FFD * 2;
    bf16* ffn1   = (bf16*)d_ws;                  // alias [normed|proj|attnb]
    float* kvsum = out1;                         // alias out1 region (attn)
    float* kvpref= kvsum  + (size_t)BH * NCH * 1024;
    float* kssum = kvpref + (size_t)BH * NCH * 1024;
    float* kspref= kssum  + (size_t)BH * NCH * 32;
    // split-K bf16 partials
    bf16*  c_p0  = (bf16*)d_out;
    bf16*  c_p1  = (bf16*)out1;
    bf16*  m_p0  = (bf16*)d_out;
    bf16*  m_p1  = (bf16*)d_out + (size_t)MROWS * DD;
    bf16*  m_p2  = hbuf;
    bf16*  w2_p0 = cat;
    bf16*  w2_p1 = cat + (size_t)MROWS * DD;
    bf16*  w2_p2 = cat + (size_t)MROWS * DD * 2;
    bf16*  w2_p3 = hbuf;

    // 1. fused prep: LN1 + all 5 weight transposes (one dispatch)
    prep_fused<<<MROWS + 14336, 256, 0, stream>>>(
        inputs, ln1_g, ln1_b, normed,
        W_in, wt_in, W_c, wt_c, W_mix, wt_mix, W1, wt1, W2, wt2);
    // 2. proj = normed @ W_in + b_in (bf16 out)   grid (M,N)
    gemm_mfma<0><<<dim3(MROWS/128, NPROJ/128), 256, 0, stream>>>(
        normed, DD, wt_in, DD, b_in, proj, NPROJ, DD, Part4{});
    // 3. fused dwconv + attn phase A (one dispatch)
    mid_fused<<<1024 + 512, 256, 0, stream>>>(
        normed, w_t, b_t, w_p, b_p, cat, proj, mask, kvsum, kssum);
    attn_prefix<<<BH, 256, 0, stream>>>(kvsum, kssum, kvpref, kspref);
    attn_scan  <<<BH * NCH, 64, 0, stream>>>(proj, mask, kvpref, kspref, attnb);
    // 5. W_c split-2 bf16 partials, then cat[:,0:D] = bf16(P0+P1+b_c)
    gemm_mfma<4><<<dim3(MROWS/128, DD/128, 2), 256, 0, stream>>>(
        attnb, INNERD, wt_c, INNERD, nullptr, nullptr, DD, INNERD / 2,
        Part4{c_p0, c_p1, nullptr, nullptr});
    epi_wc<<<MROWS * DD / 4 / 256, 256, 0, stream>>>(c_p0, c_p1, b_c, cat);
    // 6. W_mix split-3 bf16 partials
    gemm_mfma<4><<<dim3(MROWS/128, DD/128, 3), 256, 0, stream>>>(
        cat, CATD, wt_mix, CATD, nullptr, nullptr, DD, CATD / 3,
        Part4{m_p0, m_p1, m_p2, nullptr});
    // 7. out1 = (inputs + sigmoid(gate)*(sum P + b_mix))*mask ; hbuf = LN2(out1)
    epi_mix_ln2<<<MROWS, 256, 0, stream>>>(m_p0, m_p1, m_p2, b_mix, proj, inputs,
                                           mask, ln2_g, ln2_b, out1, hbuf);
    // 8. ffn1 = gelu(hbuf @ W1 + b1) (bf16 out; aliases dead normed/proj/attnb)
    gemm_mfma<1><<<dim3(MROWS/128, FFD/128), 256, 0, stream>>>(
        hbuf, DD, wt1, DD, b1, ffn1, FFD, DD, Part4{});
    // 9. W2 split-4 bf16 partials
    gemm_mfma<4><<<dim3(MROWS/128, DD/128, 4), 256, 0, stream>>>(
        ffn1, FFD, wt2, FFD, nullptr, nullptr, DD, FFD / 4,
        Part4{w2_p0, w2_p1, w2_p2, w2_p3});
    // 10. out = (out1 + sum P + b2) * mask
    epi_w2<<<MROWS * DD / 4 / 256, 256, 0, stream>>>(out, out1, w2_p0, w2_p1,
                                                     w2_p2, w2_p3, b2, mask);
}